// Round 1
// baseline (176.018 us; speedup 1.0000x reference)
//
#include <hip/hip_runtime.h>
#include <hip/hip_bf16.h>
#include <math.h>

#define B_  2
#define T_  2048
#define D_  1024
#define H_  16
#define HD_ 64

typedef __attribute__((ext_vector_type(8))) short short8;
typedef __attribute__((ext_vector_type(4))) float f32x4;

#if __has_builtin(__builtin_amdgcn_exp2f)
#define EXP2F __builtin_amdgcn_exp2f
#else
#define EXP2F exp2f
#endif

__device__ __forceinline__ ushort f2bf(float x) {
    unsigned u = __builtin_bit_cast(unsigned, x);
    return (ushort)((u + 0x7FFFu + ((u >> 16) & 1u)) >> 16);  // RTNE
}

// round-half-up bf16 pair pack
__device__ __forceinline__ unsigned pack_bf2_fast(float a, float b) {
    unsigned ua = __builtin_bit_cast(unsigned, a) + 0x8000u;
    unsigned ub = __builtin_bit_cast(unsigned, b) + 0x8000u;
    return (ua >> 16) | (ub & 0xFFFF0000u);
}

__device__ __forceinline__ void load_lds_16B(const ushort* g, ushort* l) {
    __builtin_amdgcn_global_load_lds(
        (const __attribute__((address_space(1))) unsigned*)g,
        (__attribute__((address_space(3))) unsigned*)l, 16, 0, 0);
}

// ---------------------------------------------------------------------------
// Merged prep: [0,512) cast x->bf16; [512,1280) transpose Wqkv; [1280,1536)
// transpose Wout. Wt stores are 16B/lane (full-line coalesced).
// ---------------------------------------------------------------------------
__global__ __launch_bounds__(256)
void prep_kernel(const float* __restrict__ x, ushort* __restrict__ xb,
                 const float* __restrict__ Wqkv, ushort* __restrict__ Wqkvt,
                 const float* __restrict__ Wout, ushort* __restrict__ Woutt)
{
    __shared__ ushort Ts[64][65];
    const int bid = blockIdx.x;

    if (bid < 512) {
        const int n4 = (B_ * T_ * D_) / 4;
        for (int i = bid * 256 + threadIdx.x; i < n4; i += 512 * 256) {
            float4 v = ((const float4*)x)[i];
            ushort4 o = { f2bf(v.x), f2bf(v.y), f2bf(v.z), f2bf(v.w) };
            ((ushort4*)xb)[i] = o;
        }
        return;
    }

    const float* W; ushort* Wt; int K, M, m0, k0;
    if (bid < 1280) {
        const int t = bid - 512;           // 48 x 16 tiles
        W = Wqkv; Wt = Wqkvt; K = D_; M = 3 * D_;
        m0 = (t % 48) * 64; k0 = (t / 48) * 64;
    } else {
        const int t = bid - 1280;          // 16 x 16 tiles
        W = Wout; Wt = Woutt; K = D_; M = D_;
        m0 = (t % 16) * 64; k0 = (t / 16) * 64;
    }

    const int tr = threadIdx.x >> 4;
    const int tc = threadIdx.x & 15;
    #pragma unroll
    for (int it = 0; it < 4; it++) {
        int k = tr + it * 16;
        float4 v = *(const float4*)&W[(size_t)(k0 + k) * M + m0 + tc * 4];
        Ts[tc * 4 + 0][k] = f2bf(v.x);
        Ts[tc * 4 + 1][k] = f2bf(v.y);
        Ts[tc * 4 + 2][k] = f2bf(v.z);
        Ts[tc * 4 + 3][k] = f2bf(v.w);
    }
    __syncthreads();
    #pragma unroll
    for (int it = 0; it < 2; it++) {
        const int mr  = (threadIdx.x >> 3) + it * 32;
        const int seg = (threadIdx.x & 7) * 8;
        short8 v;
        #pragma unroll
        for (int r = 0; r < 8; r++) v[r] = (short)Ts[mr][seg + r];
        *(short8*)&Wt[(size_t)(m0 + mr) * K + k0 + seg] = v;
    }
}

// ---------------------------------------------------------------------------
// QKV GEMM: qkv = x @ WqkvT^T + b. 128x128 tile, BK=64, 4 waves (2x2),
// 4x4 16x16x32 MFMA per wave. Epilogue round-trips acc through the 32 KB
// staging LDS to emit fully-coalesced 16B/lane stores: Q,K [b,h,t,d]
// (Q pre-scaled by 0.125*log2e), Vt [b,h,d,t].
// ---------------------------------------------------------------------------
__global__ __launch_bounds__(256, 4)
void gemm_qkv(const ushort* __restrict__ A, const ushort* __restrict__ Bt,
              const float* __restrict__ bias,
              ushort* __restrict__ Qg, ushort* __restrict__ Kg,
              ushort* __restrict__ Vtg)
{
    const int K = D_;
    __shared__ __align__(16) ushort lds[16384];   // staging, reused by epilogue
    ushort* Asl = lds;
    ushort* Bsl = lds + 8192;

    const int tid = threadIdx.x;
    const int w  = tid >> 6, L = tid & 63;
    const int lt = L & 15, lq = L >> 4;
    const int wr = w >> 1, wc = w & 1;
    const int m0 = blockIdx.x * 128, n0 = blockIdx.y * 128;
    const int rsub = L >> 3;
    const int pgr  = L & 7;

    f32x4 acc[4][4] = {};

    for (int k0 = 0; k0 < K; k0 += 64) {
        __syncthreads();
        #pragma unroll
        for (int j = 0; j < 4; j++) {
            const int row  = (w * 4 + j) * 8 + rsub;
            const int gran = pgr ^ rsub;
            load_lds_16B(A  + (size_t)(n0 + row) * K + k0 + gran * 8,
                         &Asl[row * 64 + pgr * 8]);
            load_lds_16B(Bt + (size_t)(m0 + row) * K + k0 + gran * 8,
                         &Bsl[row * 64 + pgr * 8]);
        }
        __syncthreads();

        #pragma unroll
        for (int ks = 0; ks < 2; ks++) {
            short8 af[4], bf[4];
            #pragma unroll
            for (int i = 0; i < 4; i++) {
                const int ra = wr * 64 + i * 16 + lt;
                af[i] = *(const short8*)&Asl[ra * 64 + (((ks * 4 + lq) ^ (ra & 7)) * 8)];
                const int rb = wc * 64 + i * 16 + lt;
                bf[i] = *(const short8*)&Bsl[rb * 64 + (((ks * 4 + lq) ^ (rb & 7)) * 8)];
            }
            #pragma unroll
            for (int i = 0; i < 4; i++)
                #pragma unroll
                for (int j = 0; j < 4; j++)
                    acc[i][j] = __builtin_amdgcn_mfma_f32_16x16x32_bf16(af[i], bf[j], acc[i][j], 0, 0, 0);
        }
    }

    __syncthreads();   // staging reads complete; reuse lds for epilogue
    const int s  = m0 >> 10;                       // block-uniform
    const int h0 = (m0 & 1023) >> 6;               // first of 2 heads
    const float qs = (s == 0) ? 0.18033688011112042f : 1.0f;   // 0.125*log2(e)

    if (s < 2) {
        // LDS[n][m] bf16 (stride 128); scalar writes are lane-consecutive in m
        #pragma unroll
        for (int j = 0; j < 4; j++) {
            const int m  = wc * 64 + j * 16 + lt;
            const float bv = bias[m0 + m];
            #pragma unroll
            for (int i = 0; i < 4; i++) {
                const int n = wr * 64 + i * 16 + lq * 4;
                #pragma unroll
                for (int r = 0; r < 4; r++)
                    lds[(n + r) * 128 + m] = f2bf((acc[i][j][r] + bv) * qs);
            }
        }
        __syncthreads();
        ushort* dst = (s == 0 ? Qg : Kg);
        #pragma unroll
        for (int it = 0; it < 8; it++) {
            const int g   = tid + it * 256;        // 0..2047
            const int row = g >> 4, c = g & 15;
            const int n = n0 + row;
            const int b = n >> 11, t = n & 2047;
            const int h = h0 + (c >> 3), d = (c & 7) * 8;
            short8 v = *(const short8*)&lds[row * 128 + c * 8];
            *(short8*)&dst[((size_t)(b * H_ + h) * T_ + t) * HD_ + d] = v;
        }
    } else {
        // LDS[m][n] bf16 (stride 128); packed b64 along n (r-consecutive)
        #pragma unroll
        for (int j = 0; j < 4; j++) {
            const int m  = wc * 64 + j * 16 + lt;
            const float bv = bias[m0 + m];
            #pragma unroll
            for (int i = 0; i < 4; i++) {
                const int n = wr * 64 + i * 16 + lq * 4;
                uint2 pk = { pack_bf2_fast(acc[i][j][0] + bv, acc[i][j][1] + bv),
                             pack_bf2_fast(acc[i][j][2] + bv, acc[i][j][3] + bv) };
                *(uint2*)&lds[m * 128 + n] = pk;
            }
        }
        __syncthreads();
        const int b = n0 >> 11, t0 = n0 & 2047;
        #pragma unroll
        for (int it = 0; it < 8; it++) {
            const int g   = tid + it * 256;
            const int row = g >> 4, c = g & 15;    // row = m, c = t-chunk
            const int h = h0 + (row >> 6), d = row & 63;
            short8 v = *(const short8*)&lds[row * 128 + c * 8];
            *(short8*)&Vtg[((size_t)(b * H_ + h) * HD_ + d) * T_ + t0 + c * 8] = v;
        }
    }
}

// ---------------------------------------------------------------------------
// Out GEMM: out = y @ WoutT^T + b. 128n x 64m tile, 512 blocks. MFMA operands
// SWAPPED (A-op = W m-rows, B-op = y n-rows) so D's reg quad = 4 consecutive
// m -> direct float4 stores, no LDS round trip.
// ---------------------------------------------------------------------------
__global__ __launch_bounds__(256, 4)
void gemm_out(const ushort* __restrict__ A, const ushort* __restrict__ Bt,
              const float* __restrict__ bias, float* __restrict__ C)
{
    const int K = D_, M = D_;
    __shared__ __align__(16) ushort lds[8192 + 4096];   // y 128x64 | W 64x64
    ushort* Asl = lds;
    ushort* Bsl = lds + 8192;

    const int tid = threadIdx.x;
    const int w  = tid >> 6, L = tid & 63;
    const int lt = L & 15, lq = L >> 4;
    const int wr = w >> 1, wc = w & 1;
    const int m0 = blockIdx.x * 64, n0 = blockIdx.y * 128;
    const int rsub = L >> 3;
    const int pgr  = L & 7;

    f32x4 acc[2][4] = {};   // [m-tile][n-tile]

    for (int k0 = 0; k0 < K; k0 += 64) {
        __syncthreads();
        #pragma unroll
        for (int j = 0; j < 4; j++) {
            const int row  = (w * 4 + j) * 8 + rsub;
            const int gran = pgr ^ rsub;
            load_lds_16B(A + (size_t)(n0 + row) * K + k0 + gran * 8,
                         &Asl[row * 64 + pgr * 8]);
        }
        #pragma unroll
        for (int j = 0; j < 2; j++) {
            const int row  = (w * 2 + j) * 8 + rsub;
            const int gran = pgr ^ rsub;
            load_lds_16B(Bt + (size_t)(m0 + row) * K + k0 + gran * 8,
                         &Bsl[row * 64 + pgr * 8]);
        }
        __syncthreads();

        #pragma unroll
        for (int ks = 0; ks < 2; ks++) {
            short8 wf[2], yf[4];
            #pragma unroll
            for (int j = 0; j < 2; j++) {
                const int rb = wc * 32 + j * 16 + lt;
                wf[j] = *(const short8*)&Bsl[rb * 64 + (((ks * 4 + lq) ^ (rb & 7)) * 8)];
            }
            #pragma unroll
            for (int i = 0; i < 4; i++) {
                const int ra = wr * 64 + i * 16 + lt;
                yf[i] = *(const short8*)&Asl[ra * 64 + (((ks * 4 + lq) ^ (ra & 7)) * 8)];
            }
            #pragma unroll
            for (int j = 0; j < 2; j++)
                #pragma unroll
                for (int i = 0; i < 4; i++)
                    acc[j][i] = __builtin_amdgcn_mfma_f32_16x16x32_bf16(wf[j], yf[i], acc[j][i], 0, 0, 0);
        }
    }

    // D layout: row (lq*4+r) = m within tile, col (lt) = n within tile
    #pragma unroll
    for (int j = 0; j < 2; j++) {
        const int mbase = m0 + wc * 32 + j * 16 + lq * 4;
        const float4 bv = *(const float4*)&bias[mbase];
        #pragma unroll
        for (int i = 0; i < 4; i++) {
            const int n = n0 + wr * 64 + i * 16 + lt;
            float4 o = { acc[j][i][0] + bv.x, acc[j][i][1] + bv.y,
                         acc[j][i][2] + bv.z, acc[j][i][3] + bv.w };
            *(float4*)&C[(size_t)n * M + mbase] = o;
        }
    }
}

// ---------------------------------------------------------------------------
// MFMA flash attention v5: 4 waves x 32 queries (2 q-groups of 16), block
// covers 128 queries = KVBLK. K/V LDS fragment reads are query-independent,
// so each a*/vf read now feeds TWO MFMAs -> ~40% fewer LDS cycles per FLOP,
// and staging passes halve (nk = qb+1 over 16 q-blocks vs (qb+2)/2 over 32).
// setprio(1) wraps MFMA clusters (T5, +4-7% measured on attn).
// ---------------------------------------------------------------------------
__global__ __launch_bounds__(256, 2)
void attn_mfma(const ushort* __restrict__ Qg, const ushort* __restrict__ Kg,
               const ushort* __restrict__ Vtg, ushort* __restrict__ yb)
{
    const int h = blockIdx.y, b = blockIdx.z;
    const int flip = ((blockIdx.y >> 3) ^ blockIdx.z) & 1;
    const int qb = flip ? blockIdx.x : (15 - blockIdx.x);   // 16 q-blocks of 128
    const int tid = threadIdx.x;
    const int w  = tid >> 6, L = tid & 63;
    const int lt = L & 15, lq = L >> 4;
    const int kswz = lt & 7;

    __shared__ __align__(16) ushort Ks [128 * 64];
    __shared__ __align__(16) ushort Vts[64 * 128];
    __shared__ __align__(16) ushort Ps [4][2][16 * 40];

    const size_t bh = (size_t)(b * H_ + h);
    const ushort* Qbase  = Qg  + bh * T_ * HD_;
    const ushort* Kbase  = Kg  + bh * T_ * HD_;
    const ushort* Vtbase = Vtg + bh * HD_ * T_;

    const int q0 = qb * 128 + w * 16 + lt;    // group-0 query (rows 0..63)
    const int q1 = q0 + 64;                   // group-1 query (rows 64..127)
    const short8 qf00 = *(const short8*)(Qbase + (size_t)q0 * HD_ + lq * 8);
    const short8 qf01 = *(const short8*)(Qbase + (size_t)q0 * HD_ + 32 + lq * 8);
    const short8 qf10 = *(const short8*)(Qbase + (size_t)q1 * HD_ + lq * 8);
    const short8 qf11 = *(const short8*)(Qbase + (size_t)q1 * HD_ + 32 + lq * 8);

    f32x4 acc0[4] = {}, acc1[4] = {};
    float lsum0 = 0.f, lsum1 = 0.f;

    const int krow = tid >> 3, kpg = tid & 7;
    const int vrow = tid >> 4, vpg = tid & 15;

    for (int kb = 0; kb <= qb; kb++) {
        __syncthreads();
        #pragma unroll
        for (int rr = 0; rr < 4; rr++) {
            const int row = krow + 32 * rr;
            load_lds_16B(Kbase + (size_t)(kb * 128 + row) * HD_ + (kpg ^ (row & 7)) * 8,
                         &Ks[row * 64 + kpg * 8]);
        }
        #pragma unroll
        for (int rr = 0; rr < 4; rr++) {
            const int d = vrow + 16 * rr;
            load_lds_16B(Vtbase + (size_t)d * T_ + kb * 128 + (vpg ^ (d & 7)) * 8,
                         &Vts[d * 128 + vpg * 8]);
        }
        __syncthreads();

        const bool lastkb = (kb == qb);       // block-uniform
        #pragma unroll
        for (int ks = 0; ks < 4; ks++) {
            const int row0 = (2 * ks) * 16 + lt;
            const int row1 = row0 + 16;
            short8 a00 = *(const short8*)&Ks[row0 * 64 + ((lq ^ kswz) * 8)];
            short8 a01 = *(const short8*)&Ks[row0 * 64 + (((4 + lq) ^ kswz) * 8)];
            short8 a10 = *(const short8*)&Ks[row1 * 64 + ((lq ^ kswz) * 8)];
            short8 a11 = *(const short8*)&Ks[row1 * 64 + (((4 + lq) ^ kswz) * 8)];
            f32x4 c00 = {}, c01 = {}, c10 = {}, c11 = {};
            __builtin_amdgcn_s_setprio(1);
            c00 = __builtin_amdgcn_mfma_f32_16x16x32_bf16(a00, qf00, c00, 0, 0, 0);
            c00 = __builtin_amdgcn_mfma_f32_16x16x32_bf16(a01, qf01, c00, 0, 0, 0);
            c01 = __builtin_amdgcn_mfma_f32_16x16x32_bf16(a10, qf00, c01, 0, 0, 0);
            c01 = __builtin_amdgcn_mfma_f32_16x16x32_bf16(a11, qf01, c01, 0, 0, 0);
            c10 = __builtin_amdgcn_mfma_f32_16x16x32_bf16(a00, qf10, c10, 0, 0, 0);
            c10 = __builtin_amdgcn_mfma_f32_16x16x32_bf16(a01, qf11, c10, 0, 0, 0);
            c11 = __builtin_amdgcn_mfma_f32_16x16x32_bf16(a10, qf10, c11, 0, 0, 0);
            c11 = __builtin_amdgcn_mfma_f32_16x16x32_bf16(a11, qf11, c11, 0, 0, 0);
            __builtin_amdgcn_s_setprio(0);

            float p0[8], p1[8];
            #pragma unroll
            for (int r = 0; r < 4; r++) {
                p0[r]     = EXP2F(c00[r]);
                p0[4 + r] = EXP2F(c01[r]);
                p1[r]     = EXP2F(c10[r]);
                p1[4 + r] = EXP2F(c11[r]);
            }
            if (lastkb) {
                const int key0 = kb * 128 + (2 * ks) * 16 + lq * 4;
                #pragma unroll
                for (int r = 0; r < 4; r++) {
                    if (key0 + r > q0)      p0[r]     = 0.f;
                    if (key0 + 16 + r > q0) p0[4 + r] = 0.f;
                    if (key0 + r > q1)      p1[r]     = 0.f;
                    if (key0 + 16 + r > q1) p1[4 + r] = 0.f;
                }
            }
            lsum0 += ((p0[0] + p0[1]) + (p0[2] + p0[3])) + ((p0[4] + p0[5]) + (p0[6] + p0[7]));
            lsum1 += ((p1[0] + p1[1]) + (p1[2] + p1[3])) + ((p1[4] + p1[5]) + (p1[6] + p1[7]));
            uint2 pk00 = { pack_bf2_fast(p0[0], p0[1]), pack_bf2_fast(p0[2], p0[3]) };
            uint2 pk01 = { pack_bf2_fast(p0[4], p0[5]), pack_bf2_fast(p0[6], p0[7]) };
            uint2 pk10 = { pack_bf2_fast(p1[0], p1[1]), pack_bf2_fast(p1[2], p1[3]) };
            uint2 pk11 = { pack_bf2_fast(p1[4], p1[5]), pack_bf2_fast(p1[6], p1[7]) };
            *(uint2*)&Ps[w][0][lt * 40 + lq * 4]      = pk00;
            *(uint2*)&Ps[w][0][lt * 40 + 16 + lq * 4] = pk01;
            *(uint2*)&Ps[w][1][lt * 40 + lq * 4]      = pk10;
            *(uint2*)&Ps[w][1][lt * 40 + 16 + lq * 4] = pk11;

            short8 pf0 = *(const short8*)&Ps[w][0][lt * 40 + lq * 8];
            short8 pf1 = *(const short8*)&Ps[w][1][lt * 40 + lq * 8];

            __builtin_amdgcn_s_setprio(1);
            #pragma unroll
            for (int dt = 0; dt < 4; dt++) {
                const int vr = dt * 16 + lt;
                short8 vf = *(const short8*)&Vts[vr * 128 + (((ks * 4 + lq) ^ kswz) * 8)];
                acc0[dt] = __builtin_amdgcn_mfma_f32_16x16x32_bf16(pf0, vf, acc0[dt], 0, 0, 0);
                acc1[dt] = __builtin_amdgcn_mfma_f32_16x16x32_bf16(pf1, vf, acc1[dt], 0, 0, 0);
            }
            __builtin_amdgcn_s_setprio(0);
        }
    }

    lsum0 += __shfl_xor(lsum0, 16, 64);
    lsum0 += __shfl_xor(lsum0, 32, 64);
    lsum1 += __shfl_xor(lsum1, 16, 64);
    lsum1 += __shfl_xor(lsum1, 32, 64);
    const float inv0 = 1.0f / lsum0;
    const float inv1 = 1.0f / lsum1;

    float linv0[4], linv1[4];
    #pragma unroll
    for (int r = 0; r < 4; r++) {
        linv0[r] = __shfl(inv0, lq * 4 + r, 64);
        linv1[r] = __shfl(inv1, lq * 4 + r, 64);
    }

    ushort* y0 = yb + (size_t)(b * T_ + qb * 128 + w * 16) * D_ + h * HD_;
    ushort* y1 = y0 + (size_t)64 * D_;
    #pragma unroll
    for (int r = 0; r < 4; r++)
        #pragma unroll
        for (int dt = 0; dt < 4; dt++) {
            y0[(size_t)(lq * 4 + r) * D_ + dt * 16 + lt] = f2bf(acc0[dt][r] * linv0[r]);
            y1[(size_t)(lq * 4 + r) * D_ + dt * 16 + lt] = f2bf(acc1[dt][r] * linv1[r]);
        }
}

// ---------------------------------------------------------------------------
extern "C" void kernel_launch(void* const* d_in, const int* in_sizes, int n_in,
                              void* d_out, int out_size, void* d_ws, size_t ws_size,
                              hipStream_t stream)
{
    const float* x    = (const float*)d_in[0];
    const float* Wqkv = (const float*)d_in[1];
    const float* bqkv = (const float*)d_in[2];
    const float* Wout = (const float*)d_in[3];
    const float* bout = (const float*)d_in[4];
    float* out = (float*)d_out;

    char* ws = (char*)d_ws;
    const size_t NT = (size_t)B_ * T_;
    ushort* xb     = (ushort*)ws;
    ushort* Wqkvt  = (ushort*)(ws + NT * D_ * 2);
    ushort* Woutt  = (ushort*)(ws + NT * D_ * 2 + (size_t)3 * D_ * D_ * 2);
    char*   p      = ws + NT * D_ * 2 + (size_t)4 * D_ * D_ * 2;
    const size_t qkv_elems = (size_t)B_ * H_ * T_ * HD_;
    ushort* Qg  = (ushort*)p;
    ushort* Kg  = (ushort*)(p + qkv_elems * 2);
    ushort* Vtg = (ushort*)(p + qkv_elems * 4);
    ushort* yb  = (ushort*)(p + qkv_elems * 6);

    prep_kernel<<<1536, 256, 0, stream>>>(x, xb, Wqkv, Wqkvt, Wout, Woutt);

    gemm_qkv<<<dim3(3 * D_ / 128, NT / 128), 256, 0, stream>>>(
        xb, Wqkvt, bqkv, Qg, Kg, Vtg);

    attn_mfma<<<dim3(16, H_, B_), 256, 0, stream>>>(Qg, Kg, Vtg, yb);

    gemm_out<<<dim3(D_ / 64, NT / 128), 256, 0, stream>>>(
        yb, Woutt, bout, out);
}

// Round 2
// 174.799 us; speedup vs baseline: 1.0070x; 1.0070x over previous
//
#include <hip/hip_runtime.h>
#include <hip/hip_bf16.h>
#include <math.h>

#define B_  2
#define T_  2048
#define D_  1024
#define H_  16
#define HD_ 64

typedef __attribute__((ext_vector_type(8))) short short8;
typedef __attribute__((ext_vector_type(4))) float f32x4;

#if __has_builtin(__builtin_amdgcn_exp2f)
#define EXP2F __builtin_amdgcn_exp2f
#else
#define EXP2F exp2f
#endif

__device__ __forceinline__ ushort f2bf(float x) {
    unsigned u = __builtin_bit_cast(unsigned, x);
    return (ushort)((u + 0x7FFFu + ((u >> 16) & 1u)) >> 16);  // RTNE
}

// round-half-up bf16 pair pack
__device__ __forceinline__ unsigned pack_bf2_fast(float a, float b) {
    unsigned ua = __builtin_bit_cast(unsigned, a) + 0x8000u;
    unsigned ub = __builtin_bit_cast(unsigned, b) + 0x8000u;
    return (ua >> 16) | (ub & 0xFFFF0000u);
}

__device__ __forceinline__ void load_lds_16B(const ushort* g, ushort* l) {
    __builtin_amdgcn_global_load_lds(
        (const __attribute__((address_space(1))) unsigned*)g,
        (__attribute__((address_space(3))) unsigned*)l, 16, 0, 0);
}

// ---------------------------------------------------------------------------
// Merged prep: [0,512) cast x->bf16; [512,1280) transpose Wqkv; [1280,1536)
// transpose Wout. Wt stores are 16B/lane (full-line coalesced).
// ---------------------------------------------------------------------------
__global__ __launch_bounds__(256)
void prep_kernel(const float* __restrict__ x, ushort* __restrict__ xb,
                 const float* __restrict__ Wqkv, ushort* __restrict__ Wqkvt,
                 const float* __restrict__ Wout, ushort* __restrict__ Woutt)
{
    __shared__ ushort Ts[64][65];
    const int bid = blockIdx.x;

    if (bid < 512) {
        const int n4 = (B_ * T_ * D_) / 4;
        for (int i = bid * 256 + threadIdx.x; i < n4; i += 512 * 256) {
            float4 v = ((const float4*)x)[i];
            ushort4 o = { f2bf(v.x), f2bf(v.y), f2bf(v.z), f2bf(v.w) };
            ((ushort4*)xb)[i] = o;
        }
        return;
    }

    const float* W; ushort* Wt; int K, M, m0, k0;
    if (bid < 1280) {
        const int t = bid - 512;           // 48 x 16 tiles
        W = Wqkv; Wt = Wqkvt; K = D_; M = 3 * D_;
        m0 = (t % 48) * 64; k0 = (t / 48) * 64;
    } else {
        const int t = bid - 1280;          // 16 x 16 tiles
        W = Wout; Wt = Woutt; K = D_; M = D_;
        m0 = (t % 16) * 64; k0 = (t / 16) * 64;
    }

    const int tr = threadIdx.x >> 4;
    const int tc = threadIdx.x & 15;
    #pragma unroll
    for (int it = 0; it < 4; it++) {
        int k = tr + it * 16;
        float4 v = *(const float4*)&W[(size_t)(k0 + k) * M + m0 + tc * 4];
        Ts[tc * 4 + 0][k] = f2bf(v.x);
        Ts[tc * 4 + 1][k] = f2bf(v.y);
        Ts[tc * 4 + 2][k] = f2bf(v.z);
        Ts[tc * 4 + 3][k] = f2bf(v.w);
    }
    __syncthreads();
    #pragma unroll
    for (int it = 0; it < 2; it++) {
        const int mr  = (threadIdx.x >> 3) + it * 32;
        const int seg = (threadIdx.x & 7) * 8;
        short8 v;
        #pragma unroll
        for (int r = 0; r < 8; r++) v[r] = (short)Ts[mr][seg + r];
        *(short8*)&Wt[(size_t)(m0 + mr) * K + k0 + seg] = v;
    }
}

// ---------------------------------------------------------------------------
// QKV GEMM: qkv = x @ WqkvT^T + b. 128x128 tile, BK=64, 4 waves (2x2),
// 4x4 16x16x32 MFMA per wave. Epilogue round-trips acc through the 32 KB
// staging LDS to emit fully-coalesced 16B/lane stores: Q,K [b,h,t,d]
// (Q pre-scaled by 0.125*log2e), Vt [b,h,d,t].
// ---------------------------------------------------------------------------
__global__ __launch_bounds__(256, 4)
void gemm_qkv(const ushort* __restrict__ A, const ushort* __restrict__ Bt,
              const float* __restrict__ bias,
              ushort* __restrict__ Qg, ushort* __restrict__ Kg,
              ushort* __restrict__ Vtg)
{
    const int K = D_;
    __shared__ __align__(16) ushort lds[16384];   // staging, reused by epilogue
    ushort* Asl = lds;
    ushort* Bsl = lds + 8192;

    const int tid = threadIdx.x;
    const int w  = tid >> 6, L = tid & 63;
    const int lt = L & 15, lq = L >> 4;
    const int wr = w >> 1, wc = w & 1;
    const int m0 = blockIdx.x * 128, n0 = blockIdx.y * 128;
    const int rsub = L >> 3;
    const int pgr  = L & 7;

    f32x4 acc[4][4] = {};

    for (int k0 = 0; k0 < K; k0 += 64) {
        __syncthreads();
        #pragma unroll
        for (int j = 0; j < 4; j++) {
            const int row  = (w * 4 + j) * 8 + rsub;
            const int gran = pgr ^ rsub;
            load_lds_16B(A  + (size_t)(n0 + row) * K + k0 + gran * 8,
                         &Asl[row * 64 + pgr * 8]);
            load_lds_16B(Bt + (size_t)(m0 + row) * K + k0 + gran * 8,
                         &Bsl[row * 64 + pgr * 8]);
        }
        __syncthreads();

        #pragma unroll
        for (int ks = 0; ks < 2; ks++) {
            short8 af[4], bf[4];
            #pragma unroll
            for (int i = 0; i < 4; i++) {
                const int ra = wr * 64 + i * 16 + lt;
                af[i] = *(const short8*)&Asl[ra * 64 + (((ks * 4 + lq) ^ (ra & 7)) * 8)];
                const int rb = wc * 64 + i * 16 + lt;
                bf[i] = *(const short8*)&Bsl[rb * 64 + (((ks * 4 + lq) ^ (rb & 7)) * 8)];
            }
            #pragma unroll
            for (int i = 0; i < 4; i++)
                #pragma unroll
                for (int j = 0; j < 4; j++)
                    acc[i][j] = __builtin_amdgcn_mfma_f32_16x16x32_bf16(af[i], bf[j], acc[i][j], 0, 0, 0);
        }
    }

    __syncthreads();   // staging reads complete; reuse lds for epilogue
    const int s  = m0 >> 10;                       // block-uniform
    const int h0 = (m0 & 1023) >> 6;               // first of 2 heads
    const float qs = (s == 0) ? 0.18033688011112042f : 1.0f;   // 0.125*log2(e)

    if (s < 2) {
        // LDS[n][m] bf16 (stride 128); scalar writes are lane-consecutive in m
        #pragma unroll
        for (int j = 0; j < 4; j++) {
            const int m  = wc * 64 + j * 16 + lt;
            const float bv = bias[m0 + m];
            #pragma unroll
            for (int i = 0; i < 4; i++) {
                const int n = wr * 64 + i * 16 + lq * 4;
                #pragma unroll
                for (int r = 0; r < 4; r++)
                    lds[(n + r) * 128 + m] = f2bf((acc[i][j][r] + bv) * qs);
            }
        }
        __syncthreads();
        ushort* dst = (s == 0 ? Qg : Kg);
        #pragma unroll
        for (int it = 0; it < 8; it++) {
            const int g   = tid + it * 256;        // 0..2047
            const int row = g >> 4, c = g & 15;
            const int n = n0 + row;
            const int b = n >> 11, t = n & 2047;
            const int h = h0 + (c >> 3), d = (c & 7) * 8;
            short8 v = *(const short8*)&lds[row * 128 + c * 8];
            *(short8*)&dst[((size_t)(b * H_ + h) * T_ + t) * HD_ + d] = v;
        }
    } else {
        // LDS[m][n] bf16 (stride 128); packed b64 along n (r-consecutive)
        #pragma unroll
        for (int j = 0; j < 4; j++) {
            const int m  = wc * 64 + j * 16 + lt;
            const float bv = bias[m0 + m];
            #pragma unroll
            for (int i = 0; i < 4; i++) {
                const int n = wr * 64 + i * 16 + lq * 4;
                uint2 pk = { pack_bf2_fast(acc[i][j][0] + bv, acc[i][j][1] + bv),
                             pack_bf2_fast(acc[i][j][2] + bv, acc[i][j][3] + bv) };
                *(uint2*)&lds[m * 128 + n] = pk;
            }
        }
        __syncthreads();
        const int b = n0 >> 11, t0 = n0 & 2047;
        #pragma unroll
        for (int it = 0; it < 8; it++) {
            const int g   = tid + it * 256;
            const int row = g >> 4, c = g & 15;    // row = m, c = t-chunk
            const int h = h0 + (row >> 6), d = row & 63;
            short8 v = *(const short8*)&lds[row * 128 + c * 8];
            *(short8*)&Vtg[((size_t)(b * H_ + h) * HD_ + d) * T_ + t0 + c * 8] = v;
        }
    }
}

// ---------------------------------------------------------------------------
// Out GEMM: out = y @ WoutT^T + b. 128n x 64m tile, 512 blocks. MFMA operands
// SWAPPED (A-op = W m-rows, B-op = y n-rows) so D's reg quad = 4 consecutive
// m -> direct float4 stores, no LDS round trip.
// ---------------------------------------------------------------------------
__global__ __launch_bounds__(256, 4)
void gemm_out(const ushort* __restrict__ A, const ushort* __restrict__ Bt,
              const float* __restrict__ bias, float* __restrict__ C)
{
    const int K = D_, M = D_;
    __shared__ __align__(16) ushort lds[8192 + 4096];   // y 128x64 | W 64x64
    ushort* Asl = lds;
    ushort* Bsl = lds + 8192;

    const int tid = threadIdx.x;
    const int w  = tid >> 6, L = tid & 63;
    const int lt = L & 15, lq = L >> 4;
    const int wr = w >> 1, wc = w & 1;
    const int m0 = blockIdx.x * 64, n0 = blockIdx.y * 128;
    const int rsub = L >> 3;
    const int pgr  = L & 7;

    f32x4 acc[2][4] = {};   // [m-tile][n-tile]

    for (int k0 = 0; k0 < K; k0 += 64) {
        __syncthreads();
        #pragma unroll
        for (int j = 0; j < 4; j++) {
            const int row  = (w * 4 + j) * 8 + rsub;
            const int gran = pgr ^ rsub;
            load_lds_16B(A + (size_t)(n0 + row) * K + k0 + gran * 8,
                         &Asl[row * 64 + pgr * 8]);
        }
        #pragma unroll
        for (int j = 0; j < 2; j++) {
            const int row  = (w * 2 + j) * 8 + rsub;
            const int gran = pgr ^ rsub;
            load_lds_16B(Bt + (size_t)(m0 + row) * K + k0 + gran * 8,
                         &Bsl[row * 64 + pgr * 8]);
        }
        __syncthreads();

        #pragma unroll
        for (int ks = 0; ks < 2; ks++) {
            short8 wf[2], yf[4];
            #pragma unroll
            for (int j = 0; j < 2; j++) {
                const int rb = wc * 32 + j * 16 + lt;
                wf[j] = *(const short8*)&Bsl[rb * 64 + (((ks * 4 + lq) ^ (rb & 7)) * 8)];
            }
            #pragma unroll
            for (int i = 0; i < 4; i++) {
                const int ra = wr * 64 + i * 16 + lt;
                yf[i] = *(const short8*)&Asl[ra * 64 + (((ks * 4 + lq) ^ (ra & 7)) * 8)];
            }
            #pragma unroll
            for (int j = 0; j < 2; j++)
                #pragma unroll
                for (int i = 0; i < 4; i++)
                    acc[j][i] = __builtin_amdgcn_mfma_f32_16x16x32_bf16(wf[j], yf[i], acc[j][i], 0, 0, 0);
        }
    }

    // D layout: row (lq*4+r) = m within tile, col (lt) = n within tile
    #pragma unroll
    for (int j = 0; j < 2; j++) {
        const int mbase = m0 + wc * 32 + j * 16 + lq * 4;
        const float4 bv = *(const float4*)&bias[mbase];
        #pragma unroll
        for (int i = 0; i < 4; i++) {
            const int n = n0 + wr * 64 + i * 16 + lt;
            float4 o = { acc[j][i][0] + bv.x, acc[j][i][1] + bv.y,
                         acc[j][i][2] + bv.z, acc[j][i][3] + bv.w };
            *(float4*)&C[(size_t)n * M + mbase] = o;
        }
    }
}

// ---------------------------------------------------------------------------
// MFMA flash attention v6: 4 waves x 32 queries (2 q-groups of 16), 128-q
// blocks, PLUS double-buffered K/V staging with raw s_barrier + counted
// s_waitcnt vmcnt(8) (T3 minimum-2-phase). __syncthreads' vmcnt(0) drain was
// the round-1 regression: staging latency fully exposed at 8 waves/CU. Now
// next tile's 8 global_load_lds stay in flight across the whole compute
// phase; vmcnt(8) drains only the current tile's loads.
// ---------------------------------------------------------------------------
__global__ __launch_bounds__(256, 2)
void attn_mfma(const ushort* __restrict__ Qg, const ushort* __restrict__ Kg,
               const ushort* __restrict__ Vtg, ushort* __restrict__ yb)
{
    const int h = blockIdx.y, b = blockIdx.z;
    const int flip = ((blockIdx.y >> 3) ^ blockIdx.z) & 1;
    const int qb = flip ? blockIdx.x : (15 - blockIdx.x);   // 16 q-blocks of 128
    const int tid = threadIdx.x;
    const int w  = tid >> 6, L = tid & 63;
    const int lt = L & 15, lq = L >> 4;
    const int kswz = lt & 7;

    __shared__ __align__(16) ushort Ks [2][128 * 64];
    __shared__ __align__(16) ushort Vts[2][64 * 128];
    __shared__ __align__(16) ushort Ps [4][2][16 * 40];

    const size_t bh = (size_t)(b * H_ + h);
    const ushort* Qbase  = Qg  + bh * T_ * HD_;
    const ushort* Kbase  = Kg  + bh * T_ * HD_;
    const ushort* Vtbase = Vtg + bh * HD_ * T_;

    const int q0 = qb * 128 + w * 16 + lt;    // group-0 query (rows 0..63)
    const int q1 = q0 + 64;                   // group-1 query (rows 64..127)
    const short8 qf00 = *(const short8*)(Qbase + (size_t)q0 * HD_ + lq * 8);
    const short8 qf01 = *(const short8*)(Qbase + (size_t)q0 * HD_ + 32 + lq * 8);
    const short8 qf10 = *(const short8*)(Qbase + (size_t)q1 * HD_ + lq * 8);
    const short8 qf11 = *(const short8*)(Qbase + (size_t)q1 * HD_ + 32 + lq * 8);

    f32x4 acc0[4] = {}, acc1[4] = {};
    float lsum0 = 0.f, lsum1 = 0.f;

    const int krow = tid >> 3, kpg = tid & 7;
    const int vrow = tid >> 4, vpg = tid & 15;

    // 8 global_load_lds per lane per tile (4 K-rows + 4 V-rows)
    auto STAGE = [&](int kb, int buf) {
        ushort* KsD  = &Ks [buf][0];
        ushort* VtsD = &Vts[buf][0];
        #pragma unroll
        for (int rr = 0; rr < 4; rr++) {
            const int row = krow + 32 * rr;
            load_lds_16B(Kbase + (size_t)(kb * 128 + row) * HD_ + (kpg ^ (row & 7)) * 8,
                         &KsD[row * 64 + kpg * 8]);
        }
        #pragma unroll
        for (int rr = 0; rr < 4; rr++) {
            const int d = vrow + 16 * rr;
            load_lds_16B(Vtbase + (size_t)d * T_ + kb * 128 + (vpg ^ (d & 7)) * 8,
                         &VtsD[d * 128 + vpg * 8]);
        }
    };

    STAGE(0, 0);                 // prologue prefetch
    int cur = 0;

    for (int kb = 0; kb <= qb; kb++) {
        if (kb < qb) {
            STAGE(kb + 1, cur ^ 1);                       // prefetch next tile
            asm volatile("s_waitcnt vmcnt(8)" ::: "memory");  // drain cur tile only
        } else {
            asm volatile("s_waitcnt vmcnt(0)" ::: "memory");
        }
        __builtin_amdgcn_s_barrier();       // all waves' cur-tile loads in LDS
        __builtin_amdgcn_sched_barrier(0);  // no ds_read hoist above barrier

        const ushort* Ksc  = &Ks [cur][0];
        const ushort* Vtsc = &Vts[cur][0];
        const bool lastkb = (kb == qb);     // block-uniform
        #pragma unroll
        for (int ks = 0; ks < 4; ks++) {
            const int row0 = (2 * ks) * 16 + lt;
            const int row1 = row0 + 16;
            short8 a00 = *(const short8*)&Ksc[row0 * 64 + ((lq ^ kswz) * 8)];
            short8 a01 = *(const short8*)&Ksc[row0 * 64 + (((4 + lq) ^ kswz) * 8)];
            short8 a10 = *(const short8*)&Ksc[row1 * 64 + ((lq ^ kswz) * 8)];
            short8 a11 = *(const short8*)&Ksc[row1 * 64 + (((4 + lq) ^ kswz) * 8)];
            f32x4 c00 = {}, c01 = {}, c10 = {}, c11 = {};
            __builtin_amdgcn_s_setprio(1);
            c00 = __builtin_amdgcn_mfma_f32_16x16x32_bf16(a00, qf00, c00, 0, 0, 0);
            c00 = __builtin_amdgcn_mfma_f32_16x16x32_bf16(a01, qf01, c00, 0, 0, 0);
            c01 = __builtin_amdgcn_mfma_f32_16x16x32_bf16(a10, qf00, c01, 0, 0, 0);
            c01 = __builtin_amdgcn_mfma_f32_16x16x32_bf16(a11, qf01, c01, 0, 0, 0);
            c10 = __builtin_amdgcn_mfma_f32_16x16x32_bf16(a00, qf10, c10, 0, 0, 0);
            c10 = __builtin_amdgcn_mfma_f32_16x16x32_bf16(a01, qf11, c10, 0, 0, 0);
            c11 = __builtin_amdgcn_mfma_f32_16x16x32_bf16(a10, qf10, c11, 0, 0, 0);
            c11 = __builtin_amdgcn_mfma_f32_16x16x32_bf16(a11, qf11, c11, 0, 0, 0);
            __builtin_amdgcn_s_setprio(0);

            float p0[8], p1[8];
            #pragma unroll
            for (int r = 0; r < 4; r++) {
                p0[r]     = EXP2F(c00[r]);
                p0[4 + r] = EXP2F(c01[r]);
                p1[r]     = EXP2F(c10[r]);
                p1[4 + r] = EXP2F(c11[r]);
            }
            if (lastkb) {
                const int key0 = kb * 128 + (2 * ks) * 16 + lq * 4;
                #pragma unroll
                for (int r = 0; r < 4; r++) {
                    if (key0 + r > q0)      p0[r]     = 0.f;
                    if (key0 + 16 + r > q0) p0[4 + r] = 0.f;
                    if (key0 + r > q1)      p1[r]     = 0.f;
                    if (key0 + 16 + r > q1) p1[4 + r] = 0.f;
                }
            }
            lsum0 += ((p0[0] + p0[1]) + (p0[2] + p0[3])) + ((p0[4] + p0[5]) + (p0[6] + p0[7]));
            lsum1 += ((p1[0] + p1[1]) + (p1[2] + p1[3])) + ((p1[4] + p1[5]) + (p1[6] + p1[7]));
            uint2 pk00 = { pack_bf2_fast(p0[0], p0[1]), pack_bf2_fast(p0[2], p0[3]) };
            uint2 pk01 = { pack_bf2_fast(p0[4], p0[5]), pack_bf2_fast(p0[6], p0[7]) };
            uint2 pk10 = { pack_bf2_fast(p1[0], p1[1]), pack_bf2_fast(p1[2], p1[3]) };
            uint2 pk11 = { pack_bf2_fast(p1[4], p1[5]), pack_bf2_fast(p1[6], p1[7]) };
            *(uint2*)&Ps[w][0][lt * 40 + lq * 4]      = pk00;
            *(uint2*)&Ps[w][0][lt * 40 + 16 + lq * 4] = pk01;
            *(uint2*)&Ps[w][1][lt * 40 + lq * 4]      = pk10;
            *(uint2*)&Ps[w][1][lt * 40 + 16 + lq * 4] = pk11;

            short8 pf0 = *(const short8*)&Ps[w][0][lt * 40 + lq * 8];
            short8 pf1 = *(const short8*)&Ps[w][1][lt * 40 + lq * 8];

            __builtin_amdgcn_s_setprio(1);
            #pragma unroll
            for (int dt = 0; dt < 4; dt++) {
                const int vr = dt * 16 + lt;
                short8 vf = *(const short8*)&Vtsc[vr * 128 + (((ks * 4 + lq) ^ kswz) * 8)];
                acc0[dt] = __builtin_amdgcn_mfma_f32_16x16x32_bf16(pf0, vf, acc0[dt], 0, 0, 0);
                acc1[dt] = __builtin_amdgcn_mfma_f32_16x16x32_bf16(pf1, vf, acc1[dt], 0, 0, 0);
            }
            __builtin_amdgcn_s_setprio(0);
        }

        __builtin_amdgcn_s_barrier();       // reads of cur done; next STAGE may overwrite
        cur ^= 1;
    }

    lsum0 += __shfl_xor(lsum0, 16, 64);
    lsum0 += __shfl_xor(lsum0, 32, 64);
    lsum1 += __shfl_xor(lsum1, 16, 64);
    lsum1 += __shfl_xor(lsum1, 32, 64);
    const float inv0 = 1.0f / lsum0;
    const float inv1 = 1.0f / lsum1;

    float linv0[4], linv1[4];
    #pragma unroll
    for (int r = 0; r < 4; r++) {
        linv0[r] = __shfl(inv0, lq * 4 + r, 64);
        linv1[r] = __shfl(inv1, lq * 4 + r, 64);
    }

    ushort* y0 = yb + (size_t)(b * T_ + qb * 128 + w * 16) * D_ + h * HD_;
    ushort* y1 = y0 + (size_t)64 * D_;
    #pragma unroll
    for (int r = 0; r < 4; r++)
        #pragma unroll
        for (int dt = 0; dt < 4; dt++) {
            y0[(size_t)(lq * 4 + r) * D_ + dt * 16 + lt] = f2bf(acc0[dt][r] * linv0[r]);
            y1[(size_t)(lq * 4 + r) * D_ + dt * 16 + lt] = f2bf(acc1[dt][r] * linv1[r]);
        }
}

// ---------------------------------------------------------------------------
extern "C" void kernel_launch(void* const* d_in, const int* in_sizes, int n_in,
                              void* d_out, int out_size, void* d_ws, size_t ws_size,
                              hipStream_t stream)
{
    const float* x    = (const float*)d_in[0];
    const float* Wqkv = (const float*)d_in[1];
    const float* bqkv = (const float*)d_in[2];
    const float* Wout = (const float*)d_in[3];
    const float* bout = (const float*)d_in[4];
    float* out = (float*)d_out;

    char* ws = (char*)d_ws;
    const size_t NT = (size_t)B_ * T_;
    ushort* xb     = (ushort*)ws;
    ushort* Wqkvt  = (ushort*)(ws + NT * D_ * 2);
    ushort* Woutt  = (ushort*)(ws + NT * D_ * 2 + (size_t)3 * D_ * D_ * 2);
    char*   p      = ws + NT * D_ * 2 + (size_t)4 * D_ * D_ * 2;
    const size_t qkv_elems = (size_t)B_ * H_ * T_ * HD_;
    ushort* Qg  = (ushort*)p;
    ushort* Kg  = (ushort*)(p + qkv_elems * 2);
    ushort* Vtg = (ushort*)(p + qkv_elems * 4);
    ushort* yb  = (ushort*)(p + qkv_elems * 6);

    prep_kernel<<<1536, 256, 0, stream>>>(x, xb, Wqkv, Wqkvt, Wout, Woutt);

    gemm_qkv<<<dim3(3 * D_ / 128, NT / 128), 256, 0, stream>>>(
        xb, Wqkvt, bqkv, Qg, Kg, Vtg);

    attn_mfma<<<dim3(16, H_, B_), 256, 0, stream>>>(Qg, Kg, Vtg, yb);

    gemm_out<<<dim3(D_ / 64, NT / 128), 256, 0, stream>>>(
        yb, Woutt, bout, out);
}

// Round 3
// 172.291 us; speedup vs baseline: 1.0216x; 1.0146x over previous
//
#include <hip/hip_runtime.h>
#include <hip/hip_bf16.h>
#include <math.h>

#define B_  2
#define T_  2048
#define D_  1024
#define H_  16
#define HD_ 64

typedef __attribute__((ext_vector_type(8))) short short8;
typedef __attribute__((ext_vector_type(4))) float f32x4;
typedef __attribute__((ext_vector_type(4))) unsigned uint32x4;

#if __has_builtin(__builtin_amdgcn_exp2f)
#define EXP2F __builtin_amdgcn_exp2f
#else
#define EXP2F exp2f
#endif

__device__ __forceinline__ ushort f2bf(float x) {
    unsigned u = __builtin_bit_cast(unsigned, x);
    return (ushort)((u + 0x7FFFu + ((u >> 16) & 1u)) >> 16);  // RTNE
}

// round-half-up bf16 pair pack
__device__ __forceinline__ unsigned pack_bf2_fast(float a, float b) {
    unsigned ua = __builtin_bit_cast(unsigned, a) + 0x8000u;
    unsigned ub = __builtin_bit_cast(unsigned, b) + 0x8000u;
    return (ua >> 16) | (ub & 0xFFFF0000u);
}

__device__ __forceinline__ void load_lds_16B(const ushort* g, ushort* l) {
    __builtin_amdgcn_global_load_lds(
        (const __attribute__((address_space(1))) unsigned*)g,
        (__attribute__((address_space(3))) unsigned*)l, 16, 0, 0);
}

// ---------------------------------------------------------------------------
// Merged prep: [0,512) cast x->bf16; [512,1280) transpose Wqkv; [1280,1536)
// transpose Wout. Wt stores are 16B/lane (full-line coalesced).
// ---------------------------------------------------------------------------
__global__ __launch_bounds__(256)
void prep_kernel(const float* __restrict__ x, ushort* __restrict__ xb,
                 const float* __restrict__ Wqkv, ushort* __restrict__ Wqkvt,
                 const float* __restrict__ Wout, ushort* __restrict__ Woutt)
{
    __shared__ ushort Ts[64][65];
    const int bid = blockIdx.x;

    if (bid < 512) {
        const int n4 = (B_ * T_ * D_) / 4;
        for (int i = bid * 256 + threadIdx.x; i < n4; i += 512 * 256) {
            float4 v = ((const float4*)x)[i];
            ushort4 o = { f2bf(v.x), f2bf(v.y), f2bf(v.z), f2bf(v.w) };
            ((ushort4*)xb)[i] = o;
        }
        return;
    }

    const float* W; ushort* Wt; int K, M, m0, k0;
    if (bid < 1280) {
        const int t = bid - 512;           // 48 x 16 tiles
        W = Wqkv; Wt = Wqkvt; K = D_; M = 3 * D_;
        m0 = (t % 48) * 64; k0 = (t / 48) * 64;
    } else {
        const int t = bid - 1280;          // 16 x 16 tiles
        W = Wout; Wt = Woutt; K = D_; M = D_;
        m0 = (t % 16) * 64; k0 = (t / 16) * 64;
    }

    const int tr = threadIdx.x >> 4;
    const int tc = threadIdx.x & 15;
    #pragma unroll
    for (int it = 0; it < 4; it++) {
        int k = tr + it * 16;
        float4 v = *(const float4*)&W[(size_t)(k0 + k) * M + m0 + tc * 4];
        Ts[tc * 4 + 0][k] = f2bf(v.x);
        Ts[tc * 4 + 1][k] = f2bf(v.y);
        Ts[tc * 4 + 2][k] = f2bf(v.z);
        Ts[tc * 4 + 3][k] = f2bf(v.w);
    }
    __syncthreads();
    #pragma unroll
    for (int it = 0; it < 2; it++) {
        const int mr  = (threadIdx.x >> 3) + it * 32;
        const int seg = (threadIdx.x & 7) * 8;
        short8 v;
        #pragma unroll
        for (int r = 0; r < 8; r++) v[r] = (short)Ts[mr][seg + r];
        *(short8*)&Wt[(size_t)(m0 + mr) * K + k0 + seg] = v;
    }
}

// ---------------------------------------------------------------------------
// QKV GEMM: qkv = x @ WqkvT^T + b. 128x128 tile, BK=64, 4 waves (2x2),
// 4x4 16x16x32 MFMA per wave. Epilogue round-trips acc through the 32 KB
// staging LDS to emit fully-coalesced 16B/lane stores: Q,K [b,h,t,d]
// (Q pre-scaled by 0.125*log2e), Vt [b,h,d,t].
// ---------------------------------------------------------------------------
__global__ __launch_bounds__(256, 4)
void gemm_qkv(const ushort* __restrict__ A, const ushort* __restrict__ Bt,
              const float* __restrict__ bias,
              ushort* __restrict__ Qg, ushort* __restrict__ Kg,
              ushort* __restrict__ Vtg)
{
    const int K = D_;
    __shared__ __align__(16) ushort lds[16384];   // staging, reused by epilogue
    ushort* Asl = lds;
    ushort* Bsl = lds + 8192;

    const int tid = threadIdx.x;
    const int w  = tid >> 6, L = tid & 63;
    const int lt = L & 15, lq = L >> 4;
    const int wr = w >> 1, wc = w & 1;
    const int m0 = blockIdx.x * 128, n0 = blockIdx.y * 128;
    const int rsub = L >> 3;
    const int pgr  = L & 7;

    f32x4 acc[4][4] = {};

    for (int k0 = 0; k0 < K; k0 += 64) {
        __syncthreads();
        #pragma unroll
        for (int j = 0; j < 4; j++) {
            const int row  = (w * 4 + j) * 8 + rsub;
            const int gran = pgr ^ rsub;
            load_lds_16B(A  + (size_t)(n0 + row) * K + k0 + gran * 8,
                         &Asl[row * 64 + pgr * 8]);
            load_lds_16B(Bt + (size_t)(m0 + row) * K + k0 + gran * 8,
                         &Bsl[row * 64 + pgr * 8]);
        }
        __syncthreads();

        #pragma unroll
        for (int ks = 0; ks < 2; ks++) {
            short8 af[4], bf[4];
            #pragma unroll
            for (int i = 0; i < 4; i++) {
                const int ra = wr * 64 + i * 16 + lt;
                af[i] = *(const short8*)&Asl[ra * 64 + (((ks * 4 + lq) ^ (ra & 7)) * 8)];
                const int rb = wc * 64 + i * 16 + lt;
                bf[i] = *(const short8*)&Bsl[rb * 64 + (((ks * 4 + lq) ^ (rb & 7)) * 8)];
            }
            #pragma unroll
            for (int i = 0; i < 4; i++)
                #pragma unroll
                for (int j = 0; j < 4; j++)
                    acc[i][j] = __builtin_amdgcn_mfma_f32_16x16x32_bf16(af[i], bf[j], acc[i][j], 0, 0, 0);
        }
    }

    __syncthreads();   // staging reads complete; reuse lds for epilogue
    const int s  = m0 >> 10;                       // block-uniform
    const int h0 = (m0 & 1023) >> 6;               // first of 2 heads
    const float qs = (s == 0) ? 0.18033688011112042f : 1.0f;   // 0.125*log2(e)

    if (s < 2) {
        // LDS[n][m] bf16 (stride 128); scalar writes are lane-consecutive in m
        #pragma unroll
        for (int j = 0; j < 4; j++) {
            const int m  = wc * 64 + j * 16 + lt;
            const float bv = bias[m0 + m];
            #pragma unroll
            for (int i = 0; i < 4; i++) {
                const int n = wr * 64 + i * 16 + lq * 4;
                #pragma unroll
                for (int r = 0; r < 4; r++)
                    lds[(n + r) * 128 + m] = f2bf((acc[i][j][r] + bv) * qs);
            }
        }
        __syncthreads();
        ushort* dst = (s == 0 ? Qg : Kg);
        #pragma unroll
        for (int it = 0; it < 8; it++) {
            const int g   = tid + it * 256;        // 0..2047
            const int row = g >> 4, c = g & 15;
            const int n = n0 + row;
            const int b = n >> 11, t = n & 2047;
            const int h = h0 + (c >> 3), d = (c & 7) * 8;
            short8 v = *(const short8*)&lds[row * 128 + c * 8];
            *(short8*)&dst[((size_t)(b * H_ + h) * T_ + t) * HD_ + d] = v;
        }
    } else {
        // LDS[m][n] bf16 (stride 128); packed b64 along n (r-consecutive)
        #pragma unroll
        for (int j = 0; j < 4; j++) {
            const int m  = wc * 64 + j * 16 + lt;
            const float bv = bias[m0 + m];
            #pragma unroll
            for (int i = 0; i < 4; i++) {
                const int n = wr * 64 + i * 16 + lq * 4;
                uint2 pk = { pack_bf2_fast(acc[i][j][0] + bv, acc[i][j][1] + bv),
                             pack_bf2_fast(acc[i][j][2] + bv, acc[i][j][3] + bv) };
                *(uint2*)&lds[m * 128 + n] = pk;
            }
        }
        __syncthreads();
        const int b = n0 >> 11, t0 = n0 & 2047;
        #pragma unroll
        for (int it = 0; it < 8; it++) {
            const int g   = tid + it * 256;
            const int row = g >> 4, c = g & 15;    // row = m, c = t-chunk
            const int h = h0 + (row >> 6), d = row & 63;
            short8 v = *(const short8*)&lds[row * 128 + c * 8];
            *(short8*)&Vtg[((size_t)(b * H_ + h) * HD_ + d) * T_ + t0 + c * 8] = v;
        }
    }
}

// ---------------------------------------------------------------------------
// Out GEMM: out = y @ WoutT^T + b. 128n x 64m tile, 512 blocks. MFMA operands
// SWAPPED (A-op = W m-rows, B-op = y n-rows) so D's reg quad = 4 consecutive
// m -> direct float4 stores, no LDS round trip.
// ---------------------------------------------------------------------------
__global__ __launch_bounds__(256, 4)
void gemm_out(const ushort* __restrict__ A, const ushort* __restrict__ Bt,
              const float* __restrict__ bias, float* __restrict__ C)
{
    const int K = D_, M = D_;
    __shared__ __align__(16) ushort lds[8192 + 4096];   // y 128x64 | W 64x64
    ushort* Asl = lds;
    ushort* Bsl = lds + 8192;

    const int tid = threadIdx.x;
    const int w  = tid >> 6, L = tid & 63;
    const int lt = L & 15, lq = L >> 4;
    const int wr = w >> 1, wc = w & 1;
    const int m0 = blockIdx.x * 64, n0 = blockIdx.y * 128;
    const int rsub = L >> 3;
    const int pgr  = L & 7;

    f32x4 acc[2][4] = {};   // [m-tile][n-tile]

    for (int k0 = 0; k0 < K; k0 += 64) {
        __syncthreads();
        #pragma unroll
        for (int j = 0; j < 4; j++) {
            const int row  = (w * 4 + j) * 8 + rsub;
            const int gran = pgr ^ rsub;
            load_lds_16B(A + (size_t)(n0 + row) * K + k0 + gran * 8,
                         &Asl[row * 64 + pgr * 8]);
        }
        #pragma unroll
        for (int j = 0; j < 2; j++) {
            const int row  = (w * 2 + j) * 8 + rsub;
            const int gran = pgr ^ rsub;
            load_lds_16B(Bt + (size_t)(m0 + row) * K + k0 + gran * 8,
                         &Bsl[row * 64 + pgr * 8]);
        }
        __syncthreads();

        #pragma unroll
        for (int ks = 0; ks < 2; ks++) {
            short8 wf[2], yf[4];
            #pragma unroll
            for (int j = 0; j < 2; j++) {
                const int rb = wc * 32 + j * 16 + lt;
                wf[j] = *(const short8*)&Bsl[rb * 64 + (((ks * 4 + lq) ^ (rb & 7)) * 8)];
            }
            #pragma unroll
            for (int i = 0; i < 4; i++) {
                const int ra = wr * 64 + i * 16 + lt;
                yf[i] = *(const short8*)&Asl[ra * 64 + (((ks * 4 + lq) ^ (ra & 7)) * 8)];
            }
            #pragma unroll
            for (int j = 0; j < 2; j++)
                #pragma unroll
                for (int i = 0; i < 4; i++)
                    acc[j][i] = __builtin_amdgcn_mfma_f32_16x16x32_bf16(wf[j], yf[i], acc[j][i], 0, 0, 0);
        }
    }

    // D layout: row (lq*4+r) = m within tile, col (lt) = n within tile
    #pragma unroll
    for (int j = 0; j < 2; j++) {
        const int mbase = m0 + wc * 32 + j * 16 + lq * 4;
        const float4 bv = *(const float4*)&bias[mbase];
        #pragma unroll
        for (int i = 0; i < 4; i++) {
            const int n = n0 + wr * 64 + i * 16 + lt;
            float4 o = { acc[j][i][0] + bv.x, acc[j][i][1] + bv.y,
                         acc[j][i][2] + bv.z, acc[j][i][3] + bv.w };
            *(float4*)&C[(size_t)n * M + mbase] = o;
        }
    }
}

// ---------------------------------------------------------------------------
// MFMA flash attention v7: zero-shuffle PV. K rows are fed to the QK^T MFMA
// in PERMUTED order (tile row p -> key (p>>2)*8 + (p&3) for c00, +4 for c01)
// so lane (lq,lt) ends up holding P for exactly keys lq*8..lq*8+7 -- the PV
// A-fragment k-slice. P is packed to bf16 in registers; the Ps LDS round
// trip (24 DS-ops/wave-tile, 43% of LDS traffic, mid-chain lgkm wait) is
// GONE. K-stage swizzle adjusted to ((row>>3)&1)*4 | (row&3) so the new
// read rows keep the same 8-way chunk spread (read-side swz == lt&7 as
// before). V path, lsum reduction, epilogue unchanged.
// ---------------------------------------------------------------------------
__global__ __launch_bounds__(256, 2)
void attn_mfma(const ushort* __restrict__ Qg, const ushort* __restrict__ Kg,
               const ushort* __restrict__ Vtg, ushort* __restrict__ yb)
{
    const int h = blockIdx.y, b = blockIdx.z;
    const int flip = ((blockIdx.y >> 3) ^ blockIdx.z) & 1;
    const int qb = flip ? blockIdx.x : (15 - blockIdx.x);   // 16 q-blocks of 128
    const int tid = threadIdx.x;
    const int w  = tid >> 6, L = tid & 63;
    const int lt = L & 15, lq = L >> 4;
    const int kswz = lt & 7;

    __shared__ __align__(16) ushort Ks [2][128 * 64];
    __shared__ __align__(16) ushort Vts[2][64 * 128];

    const size_t bh = (size_t)(b * H_ + h);
    const ushort* Qbase  = Qg  + bh * T_ * HD_;
    const ushort* Kbase  = Kg  + bh * T_ * HD_;
    const ushort* Vtbase = Vtg + bh * HD_ * T_;

    const int q0 = qb * 128 + w * 16 + lt;    // group-0 query (rows 0..63)
    const int q1 = q0 + 64;                   // group-1 query (rows 64..127)
    const short8 qf00 = *(const short8*)(Qbase + (size_t)q0 * HD_ + lq * 8);
    const short8 qf01 = *(const short8*)(Qbase + (size_t)q0 * HD_ + 32 + lq * 8);
    const short8 qf10 = *(const short8*)(Qbase + (size_t)q1 * HD_ + lq * 8);
    const short8 qf11 = *(const short8*)(Qbase + (size_t)q1 * HD_ + 32 + lq * 8);

    f32x4 acc0[4] = {}, acc1[4] = {};
    float lsum0 = 0.f, lsum1 = 0.f;

    const int krow = tid >> 3, kpg = tid & 7;
    const int vrow = tid >> 4, vpg = tid & 15;

    // 8 global_load_lds per lane per tile (4 K-rows + 4 V-rows).
    // K swizzle: chunk stored at kpg holds d-chunk kpg ^ swzK(row),
    // swzK(row) = ((row>>3)&1)*4 | (row&3)  (== lt&7 at all read sites).
    auto STAGE = [&](int kb, int buf) {
        ushort* KsD  = &Ks [buf][0];
        ushort* VtsD = &Vts[buf][0];
        #pragma unroll
        for (int rr = 0; rr < 4; rr++) {
            const int row = krow + 32 * rr;
            const int swzK = (((row >> 3) & 1) * 4) | (row & 3);
            load_lds_16B(Kbase + (size_t)(kb * 128 + row) * HD_ + (kpg ^ swzK) * 8,
                         &KsD[row * 64 + kpg * 8]);
        }
        #pragma unroll
        for (int rr = 0; rr < 4; rr++) {
            const int d = vrow + 16 * rr;
            load_lds_16B(Vtbase + (size_t)d * T_ + kb * 128 + (vpg ^ (d & 7)) * 8,
                         &VtsD[d * 128 + vpg * 8]);
        }
    };

    STAGE(0, 0);                 // prologue prefetch
    int cur = 0;

    for (int kb = 0; kb <= qb; kb++) {
        if (kb < qb) {
            STAGE(kb + 1, cur ^ 1);                       // prefetch next tile
            asm volatile("s_waitcnt vmcnt(8)" ::: "memory");  // drain cur tile only
        } else {
            asm volatile("s_waitcnt vmcnt(0)" ::: "memory");
        }
        __builtin_amdgcn_s_barrier();       // all waves' cur-tile loads in LDS
        __builtin_amdgcn_sched_barrier(0);  // no ds_read hoist above barrier

        const ushort* Ksc  = &Ks [cur][0];
        const ushort* Vtsc = &Vts[cur][0];
        const bool lastkb = (kb == qb);     // block-uniform
        #pragma unroll
        for (int ks = 0; ks < 4; ks++) {
            // Permuted key rows: c00 tile row p=lt -> key (p>>2)*8+(p&3);
            // c01 = same + 4. Both rows have swzK(row) == lt&7 == kswz.
            const int row0 = ks * 32 + ((lt >> 2) * 8) + (lt & 3);
            const int row1 = row0 + 4;
            short8 a00 = *(const short8*)&Ksc[row0 * 64 + ((lq ^ kswz) * 8)];
            short8 a01 = *(const short8*)&Ksc[row0 * 64 + (((4 + lq) ^ kswz) * 8)];
            short8 a10 = *(const short8*)&Ksc[row1 * 64 + ((lq ^ kswz) * 8)];
            short8 a11 = *(const short8*)&Ksc[row1 * 64 + (((4 + lq) ^ kswz) * 8)];
            f32x4 c00 = {}, c01 = {}, c10 = {}, c11 = {};
            __builtin_amdgcn_s_setprio(1);
            c00 = __builtin_amdgcn_mfma_f32_16x16x32_bf16(a00, qf00, c00, 0, 0, 0);
            c00 = __builtin_amdgcn_mfma_f32_16x16x32_bf16(a01, qf01, c00, 0, 0, 0);
            c01 = __builtin_amdgcn_mfma_f32_16x16x32_bf16(a10, qf00, c01, 0, 0, 0);
            c01 = __builtin_amdgcn_mfma_f32_16x16x32_bf16(a11, qf01, c01, 0, 0, 0);
            c10 = __builtin_amdgcn_mfma_f32_16x16x32_bf16(a00, qf10, c10, 0, 0, 0);
            c10 = __builtin_amdgcn_mfma_f32_16x16x32_bf16(a01, qf11, c10, 0, 0, 0);
            c11 = __builtin_amdgcn_mfma_f32_16x16x32_bf16(a10, qf10, c11, 0, 0, 0);
            c11 = __builtin_amdgcn_mfma_f32_16x16x32_bf16(a11, qf11, c11, 0, 0, 0);
            __builtin_amdgcn_s_setprio(0);

            // lane (lq,lt): c00[r] = P[key ks*32+lq*8+r][q=lt],
            //               c01[r] = P[key ks*32+lq*8+4+r][q=lt]
            float p0[8], p1[8];
            #pragma unroll
            for (int r = 0; r < 4; r++) {
                p0[r]     = EXP2F(c00[r]);
                p0[4 + r] = EXP2F(c01[r]);
                p1[r]     = EXP2F(c10[r]);
                p1[4 + r] = EXP2F(c11[r]);
            }
            if (lastkb) {
                const int key0 = kb * 128 + ks * 32 + lq * 8;
                #pragma unroll
                for (int r = 0; r < 4; r++) {
                    if (key0 + r > q0)     p0[r]     = 0.f;
                    if (key0 + 4 + r > q0) p0[4 + r] = 0.f;
                    if (key0 + r > q1)     p1[r]     = 0.f;
                    if (key0 + 4 + r > q1) p1[4 + r] = 0.f;
                }
            }
            lsum0 += ((p0[0] + p0[1]) + (p0[2] + p0[3])) + ((p0[4] + p0[5]) + (p0[6] + p0[7]));
            lsum1 += ((p1[0] + p1[1]) + (p1[2] + p1[3])) + ((p1[4] + p1[5]) + (p1[6] + p1[7]));

            // In-register PV A-fragments: keys lq*8..lq*8+7 in order.
            uint32x4 pw0 = { pack_bf2_fast(p0[0], p0[1]), pack_bf2_fast(p0[2], p0[3]),
                             pack_bf2_fast(p0[4], p0[5]), pack_bf2_fast(p0[6], p0[7]) };
            uint32x4 pw1 = { pack_bf2_fast(p1[0], p1[1]), pack_bf2_fast(p1[2], p1[3]),
                             pack_bf2_fast(p1[4], p1[5]), pack_bf2_fast(p1[6], p1[7]) };
            short8 pf0 = __builtin_bit_cast(short8, pw0);
            short8 pf1 = __builtin_bit_cast(short8, pw1);

            __builtin_amdgcn_s_setprio(1);
            #pragma unroll
            for (int dt = 0; dt < 4; dt++) {
                const int vr = dt * 16 + lt;
                short8 vf = *(const short8*)&Vtsc[vr * 128 + (((ks * 4 + lq) ^ kswz) * 8)];
                acc0[dt] = __builtin_amdgcn_mfma_f32_16x16x32_bf16(pf0, vf, acc0[dt], 0, 0, 0);
                acc1[dt] = __builtin_amdgcn_mfma_f32_16x16x32_bf16(pf1, vf, acc1[dt], 0, 0, 0);
            }
            __builtin_amdgcn_s_setprio(0);
        }

        __builtin_amdgcn_s_barrier();       // reads of cur done; next STAGE may overwrite
        cur ^= 1;
    }

    lsum0 += __shfl_xor(lsum0, 16, 64);
    lsum0 += __shfl_xor(lsum0, 32, 64);
    lsum1 += __shfl_xor(lsum1, 16, 64);
    lsum1 += __shfl_xor(lsum1, 32, 64);
    const float inv0 = 1.0f / lsum0;
    const float inv1 = 1.0f / lsum1;

    float linv0[4], linv1[4];
    #pragma unroll
    for (int r = 0; r < 4; r++) {
        linv0[r] = __shfl(inv0, lq * 4 + r, 64);
        linv1[r] = __shfl(inv1, lq * 4 + r, 64);
    }

    ushort* y0 = yb + (size_t)(b * T_ + qb * 128 + w * 16) * D_ + h * HD_;
    ushort* y1 = y0 + (size_t)64 * D_;
    #pragma unroll
    for (int r = 0; r < 4; r++)
        #pragma unroll
        for (int dt = 0; dt < 4; dt++) {
            y0[(size_t)(lq * 4 + r) * D_ + dt * 16 + lt] = f2bf(acc0[dt][r] * linv0[r]);
            y1[(size_t)(lq * 4 + r) * D_ + dt * 16 + lt] = f2bf(acc1[dt][r] * linv1[r]);
        }
}

// ---------------------------------------------------------------------------
extern "C" void kernel_launch(void* const* d_in, const int* in_sizes, int n_in,
                              void* d_out, int out_size, void* d_ws, size_t ws_size,
                              hipStream_t stream)
{
    const float* x    = (const float*)d_in[0];
    const float* Wqkv = (const float*)d_in[1];
    const float* bqkv = (const float*)d_in[2];
    const float* Wout = (const float*)d_in[3];
    const float* bout = (const float*)d_in[4];
    float* out = (float*)d_out;

    char* ws = (char*)d_ws;
    const size_t NT = (size_t)B_ * T_;
    ushort* xb     = (ushort*)ws;
    ushort* Wqkvt  = (ushort*)(ws + NT * D_ * 2);
    ushort* Woutt  = (ushort*)(ws + NT * D_ * 2 + (size_t)3 * D_ * D_ * 2);
    char*   p      = ws + NT * D_ * 2 + (size_t)4 * D_ * D_ * 2;
    const size_t qkv_elems = (size_t)B_ * H_ * T_ * HD_;
    ushort* Qg  = (ushort*)p;
    ushort* Kg  = (ushort*)(p + qkv_elems * 2);
    ushort* Vtg = (ushort*)(p + qkv_elems * 4);
    ushort* yb  = (ushort*)(p + qkv_elems * 6);

    prep_kernel<<<1536, 256, 0, stream>>>(x, xb, Wqkv, Wqkvt, Wout, Woutt);

    gemm_qkv<<<dim3(3 * D_ / 128, NT / 128), 256, 0, stream>>>(
        xb, Wqkvt, bqkv, Qg, Kg, Vtg);

    attn_mfma<<<dim3(16, H_, B_), 256, 0, stream>>>(Qg, Kg, Vtg, yb);

    gemm_out<<<dim3(D_ / 64, NT / 128), 256, 0, stream>>>(
        yb, Woutt, bout, out);
}

// Round 4
// 168.923 us; speedup vs baseline: 1.0420x; 1.0199x over previous
//
#include <hip/hip_runtime.h>
#include <hip/hip_bf16.h>
#include <math.h>

#define B_  2
#define T_  2048
#define D_  1024
#define H_  16
#define HD_ 64

typedef __attribute__((ext_vector_type(8))) short short8;
typedef __attribute__((ext_vector_type(4))) float f32x4;
typedef __attribute__((ext_vector_type(4))) unsigned uint32x4;

#if __has_builtin(__builtin_amdgcn_exp2f)
#define EXP2F __builtin_amdgcn_exp2f
#else
#define EXP2F exp2f
#endif

__device__ __forceinline__ ushort f2bf(float x) {
    unsigned u = __builtin_bit_cast(unsigned, x);
    return (ushort)((u + 0x7FFFu + ((u >> 16) & 1u)) >> 16);  // RTNE
}

// round-half-up bf16 pair pack
__device__ __forceinline__ unsigned pack_bf2_fast(float a, float b) {
    unsigned ua = __builtin_bit_cast(unsigned, a) + 0x8000u;
    unsigned ub = __builtin_bit_cast(unsigned, b) + 0x8000u;
    return (ua >> 16) | (ub & 0xFFFF0000u);
}

__device__ __forceinline__ void load_lds_16B(const ushort* g, ushort* l) {
    __builtin_amdgcn_global_load_lds(
        (const __attribute__((address_space(1))) unsigned*)g,
        (__attribute__((address_space(3))) unsigned*)l, 16, 0, 0);
}

// ---------------------------------------------------------------------------
// Merged prep: [0,512) cast x->bf16; [512,1280) transpose Wqkv; [1280,1536)
// transpose Wout. Wt stores are 16B/lane (full-line coalesced).
// ---------------------------------------------------------------------------
__global__ __launch_bounds__(256)
void prep_kernel(const float* __restrict__ x, ushort* __restrict__ xb,
                 const float* __restrict__ Wqkv, ushort* __restrict__ Wqkvt,
                 const float* __restrict__ Wout, ushort* __restrict__ Woutt)
{
    __shared__ ushort Ts[64][65];
    const int bid = blockIdx.x;

    if (bid < 512) {
        const int n4 = (B_ * T_ * D_) / 4;
        for (int i = bid * 256 + threadIdx.x; i < n4; i += 512 * 256) {
            float4 v = ((const float4*)x)[i];
            ushort4 o = { f2bf(v.x), f2bf(v.y), f2bf(v.z), f2bf(v.w) };
            ((ushort4*)xb)[i] = o;
        }
        return;
    }

    const float* W; ushort* Wt; int K, M, m0, k0;
    if (bid < 1280) {
        const int t = bid - 512;           // 48 x 16 tiles
        W = Wqkv; Wt = Wqkvt; K = D_; M = 3 * D_;
        m0 = (t % 48) * 64; k0 = (t / 48) * 64;
    } else {
        const int t = bid - 1280;          // 16 x 16 tiles
        W = Wout; Wt = Woutt; K = D_; M = D_;
        m0 = (t % 16) * 64; k0 = (t / 16) * 64;
    }

    const int tr = threadIdx.x >> 4;
    const int tc = threadIdx.x & 15;
    #pragma unroll
    for (int it = 0; it < 4; it++) {
        int k = tr + it * 16;
        float4 v = *(const float4*)&W[(size_t)(k0 + k) * M + m0 + tc * 4];
        Ts[tc * 4 + 0][k] = f2bf(v.x);
        Ts[tc * 4 + 1][k] = f2bf(v.y);
        Ts[tc * 4 + 2][k] = f2bf(v.z);
        Ts[tc * 4 + 3][k] = f2bf(v.w);
    }
    __syncthreads();
    #pragma unroll
    for (int it = 0; it < 2; it++) {
        const int mr  = (threadIdx.x >> 3) + it * 32;
        const int seg = (threadIdx.x & 7) * 8;
        short8 v;
        #pragma unroll
        for (int r = 0; r < 8; r++) v[r] = (short)Ts[mr][seg + r];
        *(short8*)&Wt[(size_t)(m0 + mr) * K + k0 + seg] = v;
    }
}

// ---------------------------------------------------------------------------
// QKV GEMM: qkv = x @ WqkvT^T + b. 128x128 tile, BK=64, 4 waves (2x2),
// 4x4 16x16x32 MFMA per wave. Epilogue round-trips acc through the 32 KB
// staging LDS to emit fully-coalesced 16B/lane stores: Q,K [b,h,t,d]
// (Q pre-scaled by 0.125*log2e), Vt [b,h,d,t].
// ---------------------------------------------------------------------------
__global__ __launch_bounds__(256, 4)
void gemm_qkv(const ushort* __restrict__ A, const ushort* __restrict__ Bt,
              const float* __restrict__ bias,
              ushort* __restrict__ Qg, ushort* __restrict__ Kg,
              ushort* __restrict__ Vtg)
{
    const int K = D_;
    __shared__ __align__(16) ushort lds[16384];   // staging, reused by epilogue
    ushort* Asl = lds;
    ushort* Bsl = lds + 8192;

    const int tid = threadIdx.x;
    const int w  = tid >> 6, L = tid & 63;
    const int lt = L & 15, lq = L >> 4;
    const int wr = w >> 1, wc = w & 1;
    const int m0 = blockIdx.x * 128, n0 = blockIdx.y * 128;
    const int rsub = L >> 3;
    const int pgr  = L & 7;

    f32x4 acc[4][4] = {};

    for (int k0 = 0; k0 < K; k0 += 64) {
        __syncthreads();
        #pragma unroll
        for (int j = 0; j < 4; j++) {
            const int row  = (w * 4 + j) * 8 + rsub;
            const int gran = pgr ^ rsub;
            load_lds_16B(A  + (size_t)(n0 + row) * K + k0 + gran * 8,
                         &Asl[row * 64 + pgr * 8]);
            load_lds_16B(Bt + (size_t)(m0 + row) * K + k0 + gran * 8,
                         &Bsl[row * 64 + pgr * 8]);
        }
        __syncthreads();

        #pragma unroll
        for (int ks = 0; ks < 2; ks++) {
            short8 af[4], bf[4];
            #pragma unroll
            for (int i = 0; i < 4; i++) {
                const int ra = wr * 64 + i * 16 + lt;
                af[i] = *(const short8*)&Asl[ra * 64 + (((ks * 4 + lq) ^ (ra & 7)) * 8)];
                const int rb = wc * 64 + i * 16 + lt;
                bf[i] = *(const short8*)&Bsl[rb * 64 + (((ks * 4 + lq) ^ (rb & 7)) * 8)];
            }
            #pragma unroll
            for (int i = 0; i < 4; i++)
                #pragma unroll
                for (int j = 0; j < 4; j++)
                    acc[i][j] = __builtin_amdgcn_mfma_f32_16x16x32_bf16(af[i], bf[j], acc[i][j], 0, 0, 0);
        }
    }

    __syncthreads();   // staging reads complete; reuse lds for epilogue
    const int s  = m0 >> 10;                       // block-uniform
    const int h0 = (m0 & 1023) >> 6;               // first of 2 heads
    const float qs = (s == 0) ? 0.18033688011112042f : 1.0f;   // 0.125*log2(e)

    if (s < 2) {
        // LDS[n][m] bf16 (stride 128); scalar writes are lane-consecutive in m
        #pragma unroll
        for (int j = 0; j < 4; j++) {
            const int m  = wc * 64 + j * 16 + lt;
            const float bv = bias[m0 + m];
            #pragma unroll
            for (int i = 0; i < 4; i++) {
                const int n = wr * 64 + i * 16 + lq * 4;
                #pragma unroll
                for (int r = 0; r < 4; r++)
                    lds[(n + r) * 128 + m] = f2bf((acc[i][j][r] + bv) * qs);
            }
        }
        __syncthreads();
        ushort* dst = (s == 0 ? Qg : Kg);
        #pragma unroll
        for (int it = 0; it < 8; it++) {
            const int g   = tid + it * 256;        // 0..2047
            const int row = g >> 4, c = g & 15;
            const int n = n0 + row;
            const int b = n >> 11, t = n & 2047;
            const int h = h0 + (c >> 3), d = (c & 7) * 8;
            short8 v = *(const short8*)&lds[row * 128 + c * 8];
            *(short8*)&dst[((size_t)(b * H_ + h) * T_ + t) * HD_ + d] = v;
        }
    } else {
        // LDS[m][n] bf16 (stride 128); packed b64 along n (r-consecutive)
        #pragma unroll
        for (int j = 0; j < 4; j++) {
            const int m  = wc * 64 + j * 16 + lt;
            const float bv = bias[m0 + m];
            #pragma unroll
            for (int i = 0; i < 4; i++) {
                const int n = wr * 64 + i * 16 + lq * 4;
                uint2 pk = { pack_bf2_fast(acc[i][j][0] + bv, acc[i][j][1] + bv),
                             pack_bf2_fast(acc[i][j][2] + bv, acc[i][j][3] + bv) };
                *(uint2*)&lds[m * 128 + n] = pk;
            }
        }
        __syncthreads();
        const int b = n0 >> 11, t0 = n0 & 2047;
        #pragma unroll
        for (int it = 0; it < 8; it++) {
            const int g   = tid + it * 256;
            const int row = g >> 4, c = g & 15;    // row = m, c = t-chunk
            const int h = h0 + (row >> 6), d = row & 63;
            short8 v = *(const short8*)&lds[row * 128 + c * 8];
            *(short8*)&Vtg[((size_t)(b * H_ + h) * HD_ + d) * T_ + t0 + c * 8] = v;
        }
    }
}

// ---------------------------------------------------------------------------
// Out GEMM: out = y @ WoutT^T + b. 128n x 64m tile, 512 blocks. MFMA operands
// SWAPPED (A-op = W m-rows, B-op = y n-rows) so D's reg quad = 4 consecutive
// m -> direct float4 stores, no LDS round trip.
// ---------------------------------------------------------------------------
__global__ __launch_bounds__(256, 4)
void gemm_out(const ushort* __restrict__ A, const ushort* __restrict__ Bt,
              const float* __restrict__ bias, float* __restrict__ C)
{
    const int K = D_, M = D_;
    __shared__ __align__(16) ushort lds[8192 + 4096];   // y 128x64 | W 64x64
    ushort* Asl = lds;
    ushort* Bsl = lds + 8192;

    const int tid = threadIdx.x;
    const int w  = tid >> 6, L = tid & 63;
    const int lt = L & 15, lq = L >> 4;
    const int wr = w >> 1, wc = w & 1;
    const int m0 = blockIdx.x * 64, n0 = blockIdx.y * 128;
    const int rsub = L >> 3;
    const int pgr  = L & 7;

    f32x4 acc[2][4] = {};   // [m-tile][n-tile]

    for (int k0 = 0; k0 < K; k0 += 64) {
        __syncthreads();
        #pragma unroll
        for (int j = 0; j < 4; j++) {
            const int row  = (w * 4 + j) * 8 + rsub;
            const int gran = pgr ^ rsub;
            load_lds_16B(A + (size_t)(n0 + row) * K + k0 + gran * 8,
                         &Asl[row * 64 + pgr * 8]);
        }
        #pragma unroll
        for (int j = 0; j < 2; j++) {
            const int row  = (w * 2 + j) * 8 + rsub;
            const int gran = pgr ^ rsub;
            load_lds_16B(Bt + (size_t)(m0 + row) * K + k0 + gran * 8,
                         &Bsl[row * 64 + pgr * 8]);
        }
        __syncthreads();

        #pragma unroll
        for (int ks = 0; ks < 2; ks++) {
            short8 wf[2], yf[4];
            #pragma unroll
            for (int j = 0; j < 2; j++) {
                const int rb = wc * 32 + j * 16 + lt;
                wf[j] = *(const short8*)&Bsl[rb * 64 + (((ks * 4 + lq) ^ (rb & 7)) * 8)];
            }
            #pragma unroll
            for (int i = 0; i < 4; i++) {
                const int ra = wr * 64 + i * 16 + lt;
                yf[i] = *(const short8*)&Asl[ra * 64 + (((ks * 4 + lq) ^ (ra & 7)) * 8)];
            }
            #pragma unroll
            for (int j = 0; j < 2; j++)
                #pragma unroll
                for (int i = 0; i < 4; i++)
                    acc[j][i] = __builtin_amdgcn_mfma_f32_16x16x32_bf16(wf[j], yf[i], acc[j][i], 0, 0, 0);
        }
    }

    // D layout: row (lq*4+r) = m within tile, col (lt) = n within tile
    #pragma unroll
    for (int j = 0; j < 2; j++) {
        const int mbase = m0 + wc * 32 + j * 16 + lq * 4;
        const float4 bv = *(const float4*)&bias[mbase];
        #pragma unroll
        for (int i = 0; i < 4; i++) {
            const int n = n0 + wr * 64 + i * 16 + lt;
            float4 o = { acc[j][i][0] + bv.x, acc[j][i][1] + bv.y,
                         acc[j][i][2] + bv.z, acc[j][i][3] + bv.w };
            *(float4*)&C[(size_t)n * M + mbase] = o;
        }
    }
}

// ---------------------------------------------------------------------------
// MFMA flash attention v8 = round-0 high-occupancy structure (64-q blocks,
// 16 q/wave, 1024 blocks, single-buffered staging; cross-block TLP hides
// staging latency) + round-3 zero-shuffle PV (permuted K-row feed so lane
// (lq,lt) holds P for keys lq*8..lq*8+7 in-register; no Ps LDS round trip).
// Ps removal shrinks LDS to exactly 32 KB -> 4 blocks/CU (was 3), i.e.
// 4 waves/SIMD of latency-hiding TLP.
// ---------------------------------------------------------------------------
__global__ __launch_bounds__(256, 4)
void attn_mfma(const ushort* __restrict__ Qg, const ushort* __restrict__ Kg,
               const ushort* __restrict__ Vtg, ushort* __restrict__ yb)
{
    const int h = blockIdx.y, b = blockIdx.z;
    const int flip = ((blockIdx.y >> 3) ^ blockIdx.z) & 1;
    const int qb = flip ? blockIdx.x : (31 - blockIdx.x);   // 32 q-blocks of 64
    const int tid = threadIdx.x;
    const int w  = tid >> 6, L = tid & 63;
    const int lt = L & 15, lq = L >> 4;
    const int kswz = lt & 7;

    __shared__ __align__(16) ushort Ks [128 * 64];
    __shared__ __align__(16) ushort Vts[64 * 128];

    const size_t bh = (size_t)(b * H_ + h);
    const ushort* Qbase  = Qg  + bh * T_ * HD_;
    const ushort* Kbase  = Kg  + bh * T_ * HD_;
    const ushort* Vtbase = Vtg + bh * HD_ * T_;

    const int q_glob = qb * 64 + w * 16 + lt;
    const short8 qf0 = *(const short8*)(Qbase + (size_t)q_glob * HD_ + lq * 8);
    const short8 qf1 = *(const short8*)(Qbase + (size_t)q_glob * HD_ + 32 + lq * 8);

    f32x4 acc_o[4] = {};
    float lsum = 0.f;

    const int krow = tid >> 3, kpg = tid & 7;
    const int vrow = tid >> 4, vpg = tid & 15;
    const int nk = (qb + 2) >> 1;

    for (int kb = 0; kb < nk; kb++) {
        __syncthreads();
        // K staged with swzK(row) = ((row>>3)&1)*4 | (row&3); at the permuted
        // read rows this evaluates to lt&7 == kswz (same 8-way chunk spread).
        #pragma unroll
        for (int rr = 0; rr < 4; rr++) {
            const int row = krow + 32 * rr;
            const int swzK = (((row >> 3) & 1) * 4) | (row & 3);
            load_lds_16B(Kbase + (size_t)(kb * 128 + row) * HD_ + (kpg ^ swzK) * 8,
                         &Ks[row * 64 + kpg * 8]);
        }
        #pragma unroll
        for (int rr = 0; rr < 4; rr++) {
            const int d = vrow + 16 * rr;
            load_lds_16B(Vtbase + (size_t)d * T_ + kb * 128 + (vpg ^ (d & 7)) * 8,
                         &Vts[d * 128 + vpg * 8]);
        }
        __syncthreads();

        const bool lastkb = (kb == nk - 1);
        const int ksN = (!lastkb) ? 4 : ((qb & 1) ? 4 : 2);
        const int mk0 = (qb & 1) ? 2 : 0;
        for (int ks = 0; ks < ksN; ks++) {
            // Permuted key rows: tile row p -> key (p>>2)*8 + (p&3) (c0),
            // +4 (c1). D-layout then gives lane (lq,lt) keys lq*8..lq*8+7.
            const int row0 = ks * 32 + ((lt >> 2) * 8) + (lt & 3);
            const int row1 = row0 + 4;
            short8 a00 = *(const short8*)&Ks[row0 * 64 + ((lq ^ kswz) * 8)];
            short8 a01 = *(const short8*)&Ks[row0 * 64 + (((4 + lq) ^ kswz) * 8)];
            short8 a10 = *(const short8*)&Ks[row1 * 64 + ((lq ^ kswz) * 8)];
            short8 a11 = *(const short8*)&Ks[row1 * 64 + (((4 + lq) ^ kswz) * 8)];
            f32x4 c0 = {}, c1 = {};
            __builtin_amdgcn_s_setprio(1);
            c0 = __builtin_amdgcn_mfma_f32_16x16x32_bf16(a00, qf0, c0, 0, 0, 0);
            c0 = __builtin_amdgcn_mfma_f32_16x16x32_bf16(a01, qf1, c0, 0, 0, 0);
            c1 = __builtin_amdgcn_mfma_f32_16x16x32_bf16(a10, qf0, c1, 0, 0, 0);
            c1 = __builtin_amdgcn_mfma_f32_16x16x32_bf16(a11, qf1, c1, 0, 0, 0);
            __builtin_amdgcn_s_setprio(0);

            // lane (lq,lt): c0[r] = P[key ks*32+lq*8+r][q], c1[r] = +4
            float p[8];
            #pragma unroll
            for (int r = 0; r < 4; r++) { p[r] = EXP2F(c0[r]); p[4 + r] = EXP2F(c1[r]); }
            if (lastkb && ks >= mk0) {
                const int key0 = kb * 128 + ks * 32 + lq * 8;
                #pragma unroll
                for (int r = 0; r < 4; r++) {
                    if (key0 + r > q_glob)     p[r]     = 0.f;
                    if (key0 + 4 + r > q_glob) p[4 + r] = 0.f;
                }
            }
            lsum += ((p[0] + p[1]) + (p[2] + p[3])) + ((p[4] + p[5]) + (p[6] + p[7]));

            uint32x4 pw = { pack_bf2_fast(p[0], p[1]), pack_bf2_fast(p[2], p[3]),
                            pack_bf2_fast(p[4], p[5]), pack_bf2_fast(p[6], p[7]) };
            short8 pf = __builtin_bit_cast(short8, pw);

            __builtin_amdgcn_s_setprio(1);
            #pragma unroll
            for (int dt = 0; dt < 4; dt++) {
                const int vr = dt * 16 + lt;
                short8 vf = *(const short8*)&Vts[vr * 128 + (((ks * 4 + lq) ^ kswz) * 8)];
                acc_o[dt] = __builtin_amdgcn_mfma_f32_16x16x32_bf16(pf, vf, acc_o[dt], 0, 0, 0);
            }
            __builtin_amdgcn_s_setprio(0);
        }
    }

    lsum += __shfl_xor(lsum, 16, 64);
    lsum += __shfl_xor(lsum, 32, 64);
    const float inv = 1.0f / lsum;

    float linv[4];
    #pragma unroll
    for (int r = 0; r < 4; r++) linv[r] = __shfl(inv, lq * 4 + r, 64);

    ushort* ybase = yb + (size_t)(b * T_ + qb * 64 + w * 16) * D_ + h * HD_;
    #pragma unroll
    for (int r = 0; r < 4; r++)
        #pragma unroll
        for (int dt = 0; dt < 4; dt++)
            ybase[(size_t)(lq * 4 + r) * D_ + dt * 16 + lt] = f2bf(acc_o[dt][r] * linv[r]);
}

// ---------------------------------------------------------------------------
extern "C" void kernel_launch(void* const* d_in, const int* in_sizes, int n_in,
                              void* d_out, int out_size, void* d_ws, size_t ws_size,
                              hipStream_t stream)
{
    const float* x    = (const float*)d_in[0];
    const float* Wqkv = (const float*)d_in[1];
    const float* bqkv = (const float*)d_in[2];
    const float* Wout = (const float*)d_in[3];
    const float* bout = (const float*)d_in[4];
    float* out = (float*)d_out;

    char* ws = (char*)d_ws;
    const size_t NT = (size_t)B_ * T_;
    ushort* xb     = (ushort*)ws;
    ushort* Wqkvt  = (ushort*)(ws + NT * D_ * 2);
    ushort* Woutt  = (ushort*)(ws + NT * D_ * 2 + (size_t)3 * D_ * D_ * 2);
    char*   p      = ws + NT * D_ * 2 + (size_t)4 * D_ * D_ * 2;
    const size_t qkv_elems = (size_t)B_ * H_ * T_ * HD_;
    ushort* Qg  = (ushort*)p;
    ushort* Kg  = (ushort*)(p + qkv_elems * 2);
    ushort* Vtg = (ushort*)(p + qkv_elems * 4);
    ushort* yb  = (ushort*)(p + qkv_elems * 6);

    prep_kernel<<<1536, 256, 0, stream>>>(x, xb, Wqkv, Wqkvt, Wout, Woutt);

    gemm_qkv<<<dim3(3 * D_ / 128, NT / 128), 256, 0, stream>>>(
        xb, Wqkvt, bqkv, Qg, Kg, Vtg);

    attn_mfma<<<dim3(32, H_, B_), 256, 0, stream>>>(Qg, Kg, Vtg, yb);

    gemm_out<<<dim3(D_ / 64, NT / 128), 256, 0, stream>>>(
        yb, Woutt, bout, out);
}

// Round 5
// 166.715 us; speedup vs baseline: 1.0558x; 1.0132x over previous
//
#include <hip/hip_runtime.h>
#include <hip/hip_bf16.h>
#include <math.h>

#define B_  2
#define T_  2048
#define D_  1024
#define H_  16
#define HD_ 64

typedef __attribute__((ext_vector_type(8))) short short8;
typedef __attribute__((ext_vector_type(4))) float f32x4;
typedef __attribute__((ext_vector_type(4))) unsigned uint32x4;

#if __has_builtin(__builtin_amdgcn_exp2f)
#define EXP2F __builtin_amdgcn_exp2f
#else
#define EXP2F exp2f
#endif

__device__ __forceinline__ ushort f2bf(float x) {
    unsigned u = __builtin_bit_cast(unsigned, x);
    return (ushort)((u + 0x7FFFu + ((u >> 16) & 1u)) >> 16);  // RTNE
}

// round-half-up bf16 pair pack
__device__ __forceinline__ unsigned pack_bf2_fast(float a, float b) {
    unsigned ua = __builtin_bit_cast(unsigned, a) + 0x8000u;
    unsigned ub = __builtin_bit_cast(unsigned, b) + 0x8000u;
    return (ua >> 16) | (ub & 0xFFFF0000u);
}

__device__ __forceinline__ void load_lds_16B(const ushort* g, ushort* l) {
    __builtin_amdgcn_global_load_lds(
        (const __attribute__((address_space(1))) unsigned*)g,
        (__attribute__((address_space(3))) unsigned*)l, 16, 0, 0);
}

// ---------------------------------------------------------------------------
// Merged prep: [0,512) cast x->bf16; [512,1280) transpose Wqkv; [1280,1536)
// transpose Wout. Wt stores are 16B/lane (full-line coalesced).
// ---------------------------------------------------------------------------
__global__ __launch_bounds__(256)
void prep_kernel(const float* __restrict__ x, ushort* __restrict__ xb,
                 const float* __restrict__ Wqkv, ushort* __restrict__ Wqkvt,
                 const float* __restrict__ Wout, ushort* __restrict__ Woutt)
{
    __shared__ ushort Ts[64][65];
    const int bid = blockIdx.x;

    if (bid < 512) {
        const int n4 = (B_ * T_ * D_) / 4;
        for (int i = bid * 256 + threadIdx.x; i < n4; i += 512 * 256) {
            float4 v = ((const float4*)x)[i];
            ushort4 o = { f2bf(v.x), f2bf(v.y), f2bf(v.z), f2bf(v.w) };
            ((ushort4*)xb)[i] = o;
        }
        return;
    }

    const float* W; ushort* Wt; int K, M, m0, k0;
    if (bid < 1280) {
        const int t = bid - 512;           // 48 x 16 tiles
        W = Wqkv; Wt = Wqkvt; K = D_; M = 3 * D_;
        m0 = (t % 48) * 64; k0 = (t / 48) * 64;
    } else {
        const int t = bid - 1280;          // 16 x 16 tiles
        W = Wout; Wt = Woutt; K = D_; M = D_;
        m0 = (t % 16) * 64; k0 = (t / 16) * 64;
    }

    const int tr = threadIdx.x >> 4;
    const int tc = threadIdx.x & 15;
    #pragma unroll
    for (int it = 0; it < 4; it++) {
        int k = tr + it * 16;
        float4 v = *(const float4*)&W[(size_t)(k0 + k) * M + m0 + tc * 4];
        Ts[tc * 4 + 0][k] = f2bf(v.x);
        Ts[tc * 4 + 1][k] = f2bf(v.y);
        Ts[tc * 4 + 2][k] = f2bf(v.z);
        Ts[tc * 4 + 3][k] = f2bf(v.w);
    }
    __syncthreads();
    #pragma unroll
    for (int it = 0; it < 2; it++) {
        const int mr  = (threadIdx.x >> 3) + it * 32;
        const int seg = (threadIdx.x & 7) * 8;
        short8 v;
        #pragma unroll
        for (int r = 0; r < 8; r++) v[r] = (short)Ts[mr][seg + r];
        *(short8*)&Wt[(size_t)(m0 + mr) * K + k0 + seg] = v;
    }
}

// ---------------------------------------------------------------------------
// QKV GEMM: qkv = x @ WqkvT^T + b. 128x128 tile, BK=64, 4 waves (2x2),
// 4x4 16x16x32 MFMA per wave. Epilogue round-trips acc through the 32 KB
// staging LDS to emit fully-coalesced 16B/lane stores: Q,K [b,h,t,d]
// (Q pre-scaled by 0.125*log2e), Vt [b,h,d,t].
// ---------------------------------------------------------------------------
__global__ __launch_bounds__(256, 4)
void gemm_qkv(const ushort* __restrict__ A, const ushort* __restrict__ Bt,
              const float* __restrict__ bias,
              ushort* __restrict__ Qg, ushort* __restrict__ Kg,
              ushort* __restrict__ Vtg)
{
    const int K = D_;
    __shared__ __align__(16) ushort lds[16384];   // staging, reused by epilogue
    ushort* Asl = lds;
    ushort* Bsl = lds + 8192;

    const int tid = threadIdx.x;
    const int w  = tid >> 6, L = tid & 63;
    const int lt = L & 15, lq = L >> 4;
    const int wr = w >> 1, wc = w & 1;
    const int m0 = blockIdx.x * 128, n0 = blockIdx.y * 128;
    const int rsub = L >> 3;
    const int pgr  = L & 7;

    f32x4 acc[4][4] = {};

    for (int k0 = 0; k0 < K; k0 += 64) {
        __syncthreads();
        #pragma unroll
        for (int j = 0; j < 4; j++) {
            const int row  = (w * 4 + j) * 8 + rsub;
            const int gran = pgr ^ rsub;
            load_lds_16B(A  + (size_t)(n0 + row) * K + k0 + gran * 8,
                         &Asl[row * 64 + pgr * 8]);
            load_lds_16B(Bt + (size_t)(m0 + row) * K + k0 + gran * 8,
                         &Bsl[row * 64 + pgr * 8]);
        }
        __syncthreads();

        #pragma unroll
        for (int ks = 0; ks < 2; ks++) {
            short8 af[4], bf[4];
            #pragma unroll
            for (int i = 0; i < 4; i++) {
                const int ra = wr * 64 + i * 16 + lt;
                af[i] = *(const short8*)&Asl[ra * 64 + (((ks * 4 + lq) ^ (ra & 7)) * 8)];
                const int rb = wc * 64 + i * 16 + lt;
                bf[i] = *(const short8*)&Bsl[rb * 64 + (((ks * 4 + lq) ^ (rb & 7)) * 8)];
            }
            #pragma unroll
            for (int i = 0; i < 4; i++)
                #pragma unroll
                for (int j = 0; j < 4; j++)
                    acc[i][j] = __builtin_amdgcn_mfma_f32_16x16x32_bf16(af[i], bf[j], acc[i][j], 0, 0, 0);
        }
    }

    __syncthreads();   // staging reads complete; reuse lds for epilogue
    const int s  = m0 >> 10;                       // block-uniform
    const int h0 = (m0 & 1023) >> 6;               // first of 2 heads
    const float qs = (s == 0) ? 0.18033688011112042f : 1.0f;   // 0.125*log2(e)

    if (s < 2) {
        // LDS[n][m] bf16 (stride 128); scalar writes are lane-consecutive in m
        #pragma unroll
        for (int j = 0; j < 4; j++) {
            const int m  = wc * 64 + j * 16 + lt;
            const float bv = bias[m0 + m];
            #pragma unroll
            for (int i = 0; i < 4; i++) {
                const int n = wr * 64 + i * 16 + lq * 4;
                #pragma unroll
                for (int r = 0; r < 4; r++)
                    lds[(n + r) * 128 + m] = f2bf((acc[i][j][r] + bv) * qs);
            }
        }
        __syncthreads();
        ushort* dst = (s == 0 ? Qg : Kg);
        #pragma unroll
        for (int it = 0; it < 8; it++) {
            const int g   = tid + it * 256;        // 0..2047
            const int row = g >> 4, c = g & 15;
            const int n = n0 + row;
            const int b = n >> 11, t = n & 2047;
            const int h = h0 + (c >> 3), d = (c & 7) * 8;
            short8 v = *(const short8*)&lds[row * 128 + c * 8];
            *(short8*)&dst[((size_t)(b * H_ + h) * T_ + t) * HD_ + d] = v;
        }
    } else {
        // LDS[m][n] bf16 (stride 128); packed b64 along n (r-consecutive)
        #pragma unroll
        for (int j = 0; j < 4; j++) {
            const int m  = wc * 64 + j * 16 + lt;
            const float bv = bias[m0 + m];
            #pragma unroll
            for (int i = 0; i < 4; i++) {
                const int n = wr * 64 + i * 16 + lq * 4;
                uint2 pk = { pack_bf2_fast(acc[i][j][0] + bv, acc[i][j][1] + bv),
                             pack_bf2_fast(acc[i][j][2] + bv, acc[i][j][3] + bv) };
                *(uint2*)&lds[m * 128 + n] = pk;
            }
        }
        __syncthreads();
        const int b = n0 >> 11, t0 = n0 & 2047;
        #pragma unroll
        for (int it = 0; it < 8; it++) {
            const int g   = tid + it * 256;
            const int row = g >> 4, c = g & 15;    // row = m, c = t-chunk
            const int h = h0 + (row >> 6), d = row & 63;
            short8 v = *(const short8*)&lds[row * 128 + c * 8];
            *(short8*)&Vtg[((size_t)(b * H_ + h) * HD_ + d) * T_ + t0 + c * 8] = v;
        }
    }
}

// ---------------------------------------------------------------------------
// Out GEMM: out = y @ WoutT^T + b. 128n x 64m tile, 512 blocks. MFMA operands
// SWAPPED (A-op = W m-rows, B-op = y n-rows) so D's reg quad = 4 consecutive
// m -> direct float4 stores, no LDS round trip.
// ---------------------------------------------------------------------------
__global__ __launch_bounds__(256, 4)
void gemm_out(const ushort* __restrict__ A, const ushort* __restrict__ Bt,
              const float* __restrict__ bias, float* __restrict__ C)
{
    const int K = D_, M = D_;
    __shared__ __align__(16) ushort lds[8192 + 4096];   // y 128x64 | W 64x64
    ushort* Asl = lds;
    ushort* Bsl = lds + 8192;

    const int tid = threadIdx.x;
    const int w  = tid >> 6, L = tid & 63;
    const int lt = L & 15, lq = L >> 4;
    const int wr = w >> 1, wc = w & 1;
    const int m0 = blockIdx.x * 64, n0 = blockIdx.y * 128;
    const int rsub = L >> 3;
    const int pgr  = L & 7;

    f32x4 acc[2][4] = {};   // [m-tile][n-tile]

    for (int k0 = 0; k0 < K; k0 += 64) {
        __syncthreads();
        #pragma unroll
        for (int j = 0; j < 4; j++) {
            const int row  = (w * 4 + j) * 8 + rsub;
            const int gran = pgr ^ rsub;
            load_lds_16B(A + (size_t)(n0 + row) * K + k0 + gran * 8,
                         &Asl[row * 64 + pgr * 8]);
        }
        #pragma unroll
        for (int j = 0; j < 2; j++) {
            const int row  = (w * 2 + j) * 8 + rsub;
            const int gran = pgr ^ rsub;
            load_lds_16B(Bt + (size_t)(m0 + row) * K + k0 + gran * 8,
                         &Bsl[row * 64 + pgr * 8]);
        }
        __syncthreads();

        #pragma unroll
        for (int ks = 0; ks < 2; ks++) {
            short8 wf[2], yf[4];
            #pragma unroll
            for (int j = 0; j < 2; j++) {
                const int rb = wc * 32 + j * 16 + lt;
                wf[j] = *(const short8*)&Bsl[rb * 64 + (((ks * 4 + lq) ^ (rb & 7)) * 8)];
            }
            #pragma unroll
            for (int i = 0; i < 4; i++) {
                const int ra = wr * 64 + i * 16 + lt;
                yf[i] = *(const short8*)&Asl[ra * 64 + (((ks * 4 + lq) ^ (ra & 7)) * 8)];
            }
            #pragma unroll
            for (int j = 0; j < 2; j++)
                #pragma unroll
                for (int i = 0; i < 4; i++)
                    acc[j][i] = __builtin_amdgcn_mfma_f32_16x16x32_bf16(wf[j], yf[i], acc[j][i], 0, 0, 0);
        }
    }

    // D layout: row (lq*4+r) = m within tile, col (lt) = n within tile
    #pragma unroll
    for (int j = 0; j < 2; j++) {
        const int mbase = m0 + wc * 32 + j * 16 + lq * 4;
        const float4 bv = *(const float4*)&bias[mbase];
        #pragma unroll
        for (int i = 0; i < 4; i++) {
            const int n = n0 + wr * 64 + i * 16 + lt;
            float4 o = { acc[j][i][0] + bv.x, acc[j][i][1] + bv.y,
                         acc[j][i][2] + bv.z, acc[j][i][3] + bv.w };
            *(float4*)&C[(size_t)n * M + mbase] = o;
        }
    }
}

// ---------------------------------------------------------------------------
// MFMA flash attention v9 = v8 (64-q blocks, 16 q/wave, 1024 blocks,
// 4 blocks/CU, zero-shuffle PV via permuted K-row feed) with the round-0
// TWO-BRANCH inner loop restored: non-final KV tiles run a branch-free,
// fully #pragma-unroll'ed 4x ks fast path (no mask code at all), so the
// compiler can overlap consecutive ks chains (K-read/QK-MFMA of ks+1 under
// exp2/PV of ks). v8's runtime-trip-count merged loop blocked unrolling and
// serialized the per-ks chain -- that was the round-4 regression.
// ---------------------------------------------------------------------------
__global__ __launch_bounds__(256, 4)
void attn_mfma(const ushort* __restrict__ Qg, const ushort* __restrict__ Kg,
               const ushort* __restrict__ Vtg, ushort* __restrict__ yb)
{
    const int h = blockIdx.y, b = blockIdx.z;
    const int flip = ((blockIdx.y >> 3) ^ blockIdx.z) & 1;
    const int qb = flip ? blockIdx.x : (31 - blockIdx.x);   // 32 q-blocks of 64
    const int tid = threadIdx.x;
    const int w  = tid >> 6, L = tid & 63;
    const int lt = L & 15, lq = L >> 4;
    const int kswz = lt & 7;

    __shared__ __align__(16) ushort Ks [128 * 64];
    __shared__ __align__(16) ushort Vts[64 * 128];

    const size_t bh = (size_t)(b * H_ + h);
    const ushort* Qbase  = Qg  + bh * T_ * HD_;
    const ushort* Kbase  = Kg  + bh * T_ * HD_;
    const ushort* Vtbase = Vtg + bh * HD_ * T_;

    const int q_glob = qb * 64 + w * 16 + lt;
    const short8 qf0 = *(const short8*)(Qbase + (size_t)q_glob * HD_ + lq * 8);
    const short8 qf1 = *(const short8*)(Qbase + (size_t)q_glob * HD_ + 32 + lq * 8);

    f32x4 acc_o[4] = {};
    float lsum = 0.f;

    const int krow = tid >> 3, kpg = tid & 7;
    const int vrow = tid >> 4, vpg = tid & 15;
    const int nk = (qb + 2) >> 1;

    for (int kb = 0; kb < nk; kb++) {
        __syncthreads();
        // K staged with swzK(row) = ((row>>3)&1)*4 | (row&3); at the permuted
        // read rows this evaluates to lt&7 == kswz (same 8-way chunk spread).
        #pragma unroll
        for (int rr = 0; rr < 4; rr++) {
            const int row = krow + 32 * rr;
            const int swzK = (((row >> 3) & 1) * 4) | (row & 3);
            load_lds_16B(Kbase + (size_t)(kb * 128 + row) * HD_ + (kpg ^ swzK) * 8,
                         &Ks[row * 64 + kpg * 8]);
        }
        #pragma unroll
        for (int rr = 0; rr < 4; rr++) {
            const int d = vrow + 16 * rr;
            load_lds_16B(Vtbase + (size_t)d * T_ + kb * 128 + (vpg ^ (d & 7)) * 8,
                         &Vts[d * 128 + vpg * 8]);
        }
        __syncthreads();

        if (kb < nk - 1) {
            // Branch-free fast path: all keys < every q of this block.
            #pragma unroll
            for (int ks = 0; ks < 4; ks++) {
                // Permuted key rows: tile row p -> key (p>>2)*8 + (p&3) (c0),
                // +4 (c1) => lane (lq,lt) holds keys lq*8..lq*8+7 in-register.
                const int row0 = ks * 32 + ((lt >> 2) * 8) + (lt & 3);
                const int row1 = row0 + 4;
                short8 a00 = *(const short8*)&Ks[row0 * 64 + ((lq ^ kswz) * 8)];
                short8 a01 = *(const short8*)&Ks[row0 * 64 + (((4 + lq) ^ kswz) * 8)];
                short8 a10 = *(const short8*)&Ks[row1 * 64 + ((lq ^ kswz) * 8)];
                short8 a11 = *(const short8*)&Ks[row1 * 64 + (((4 + lq) ^ kswz) * 8)];
                f32x4 c0 = {}, c1 = {};
                __builtin_amdgcn_s_setprio(1);
                c0 = __builtin_amdgcn_mfma_f32_16x16x32_bf16(a00, qf0, c0, 0, 0, 0);
                c0 = __builtin_amdgcn_mfma_f32_16x16x32_bf16(a01, qf1, c0, 0, 0, 0);
                c1 = __builtin_amdgcn_mfma_f32_16x16x32_bf16(a10, qf0, c1, 0, 0, 0);
                c1 = __builtin_amdgcn_mfma_f32_16x16x32_bf16(a11, qf1, c1, 0, 0, 0);
                __builtin_amdgcn_s_setprio(0);

                float p[8];
                #pragma unroll
                for (int r = 0; r < 4; r++) { p[r] = EXP2F(c0[r]); p[4 + r] = EXP2F(c1[r]); }
                lsum += ((p[0] + p[1]) + (p[2] + p[3])) + ((p[4] + p[5]) + (p[6] + p[7]));

                uint32x4 pw = { pack_bf2_fast(p[0], p[1]), pack_bf2_fast(p[2], p[3]),
                                pack_bf2_fast(p[4], p[5]), pack_bf2_fast(p[6], p[7]) };
                short8 pf = __builtin_bit_cast(short8, pw);

                __builtin_amdgcn_s_setprio(1);
                #pragma unroll
                for (int dt = 0; dt < 4; dt++) {
                    const int vr = dt * 16 + lt;
                    short8 vf = *(const short8*)&Vts[vr * 128 + (((ks * 4 + lq) ^ kswz) * 8)];
                    acc_o[dt] = __builtin_amdgcn_mfma_f32_16x16x32_bf16(pf, vf, acc_o[dt], 0, 0, 0);
                }
                __builtin_amdgcn_s_setprio(0);
            }
        } else {
            // Last tile: masked, runtime trip count (qb even: 2 ks, all
            // masked; qb odd: 4 ks, last 2 masked).
            const int ksN = (qb & 1) ? 4 : 2;
            const int mk0 = (qb & 1) ? 2 : 0;
            for (int ks = 0; ks < ksN; ks++) {
                const int row0 = ks * 32 + ((lt >> 2) * 8) + (lt & 3);
                const int row1 = row0 + 4;
                short8 a00 = *(const short8*)&Ks[row0 * 64 + ((lq ^ kswz) * 8)];
                short8 a01 = *(const short8*)&Ks[row0 * 64 + (((4 + lq) ^ kswz) * 8)];
                short8 a10 = *(const short8*)&Ks[row1 * 64 + ((lq ^ kswz) * 8)];
                short8 a11 = *(const short8*)&Ks[row1 * 64 + (((4 + lq) ^ kswz) * 8)];
                f32x4 c0 = {}, c1 = {};
                __builtin_amdgcn_s_setprio(1);
                c0 = __builtin_amdgcn_mfma_f32_16x16x32_bf16(a00, qf0, c0, 0, 0, 0);
                c0 = __builtin_amdgcn_mfma_f32_16x16x32_bf16(a01, qf1, c0, 0, 0, 0);
                c1 = __builtin_amdgcn_mfma_f32_16x16x32_bf16(a10, qf0, c1, 0, 0, 0);
                c1 = __builtin_amdgcn_mfma_f32_16x16x32_bf16(a11, qf1, c1, 0, 0, 0);
                __builtin_amdgcn_s_setprio(0);

                float p[8];
                #pragma unroll
                for (int r = 0; r < 4; r++) { p[r] = EXP2F(c0[r]); p[4 + r] = EXP2F(c1[r]); }
                if (ks >= mk0) {
                    const int key0 = kb * 128 + ks * 32 + lq * 8;
                    #pragma unroll
                    for (int r = 0; r < 4; r++) {
                        if (key0 + r > q_glob)     p[r]     = 0.f;
                        if (key0 + 4 + r > q_glob) p[4 + r] = 0.f;
                    }
                }
                lsum += ((p[0] + p[1]) + (p[2] + p[3])) + ((p[4] + p[5]) + (p[6] + p[7]));

                uint32x4 pw = { pack_bf2_fast(p[0], p[1]), pack_bf2_fast(p[2], p[3]),
                                pack_bf2_fast(p[4], p[5]), pack_bf2_fast(p[6], p[7]) };
                short8 pf = __builtin_bit_cast(short8, pw);

                __builtin_amdgcn_s_setprio(1);
                #pragma unroll
                for (int dt = 0; dt < 4; dt++) {
                    const int vr = dt * 16 + lt;
                    short8 vf = *(const short8*)&Vts[vr * 128 + (((ks * 4 + lq) ^ kswz) * 8)];
                    acc_o[dt] = __builtin_amdgcn_mfma_f32_16x16x32_bf16(pf, vf, acc_o[dt], 0, 0, 0);
                }
                __builtin_amdgcn_s_setprio(0);
            }
        }
    }

    lsum += __shfl_xor(lsum, 16, 64);
    lsum += __shfl_xor(lsum, 32, 64);
    const float inv = 1.0f / lsum;

    float linv[4];
    #pragma unroll
    for (int r = 0; r < 4; r++) linv[r] = __shfl(inv, lq * 4 + r, 64);

    ushort* ybase = yb + (size_t)(b * T_ + qb * 64 + w * 16) * D_ + h * HD_;
    #pragma unroll
    for (int r = 0; r < 4; r++)
        #pragma unroll
        for (int dt = 0; dt < 4; dt++)
            ybase[(size_t)(lq * 4 + r) * D_ + dt * 16 + lt] = f2bf(acc_o[dt][r] * linv[r]);
}

// ---------------------------------------------------------------------------
extern "C" void kernel_launch(void* const* d_in, const int* in_sizes, int n_in,
                              void* d_out, int out_size, void* d_ws, size_t ws_size,
                              hipStream_t stream)
{
    const float* x    = (const float*)d_in[0];
    const float* Wqkv = (const float*)d_in[1];
    const float* bqkv = (const float*)d_in[2];
    const float* Wout = (const float*)d_in[3];
    const float* bout = (const float*)d_in[4];
    float* out = (float*)d_out;

    char* ws = (char*)d_ws;
    const size_t NT = (size_t)B_ * T_;
    ushort* xb     = (ushort*)ws;
    ushort* Wqkvt  = (ushort*)(ws + NT * D_ * 2);
    ushort* Woutt  = (ushort*)(ws + NT * D_ * 2 + (size_t)3 * D_ * D_ * 2);
    char*   p      = ws + NT * D_ * 2 + (size_t)4 * D_ * D_ * 2;
    const size_t qkv_elems = (size_t)B_ * H_ * T_ * HD_;
    ushort* Qg  = (ushort*)p;
    ushort* Kg  = (ushort*)(p + qkv_elems * 2);
    ushort* Vtg = (ushort*)(p + qkv_elems * 4);
    ushort* yb  = (ushort*)(p + qkv_elems * 6);

    prep_kernel<<<1536, 256, 0, stream>>>(x, xb, Wqkv, Wqkvt, Wout, Woutt);

    gemm_qkv<<<dim3(3 * D_ / 128, NT / 128), 256, 0, stream>>>(
        xb, Wqkvt, bqkv, Qg, Kg, Vtg);

    attn_mfma<<<dim3(32, H_, B_), 256, 0, stream>>>(Qg, Kg, Vtg, yb);

    gemm_out<<<dim3(D_ / 64, NT / 128), 256, 0, stream>>>(
        yb, Woutt, bout, out);
}